// Round 2
// baseline (548.603 us; speedup 1.0000x reference)
//
#include <hip/hip_runtime.h>
#include <stdint.h>

#define DEV __device__ __forceinline__

typedef unsigned short u16;
typedef unsigned int u32;

typedef __bf16 bf16x8 __attribute__((ext_vector_type(8)));
typedef float f32x4 __attribute__((ext_vector_type(4)));
typedef u16 u16x8 __attribute__((ext_vector_type(8)));
typedef u16 u16x4 __attribute__((ext_vector_type(4)));

static_assert(sizeof(bf16x8) == 16, "bf16x8 must be 16B");

#define NT 16384      // B*S = 4*4096
#define DM 1024
#define SPAD 4098     // S + 2 halo rows per batch

DEV u16 f2bf(float f) {
  u32 u = __float_as_uint(f);
  u32 r = u + 0x7FFFu + ((u >> 16) & 1u);
  return (u16)(r >> 16);
}
DEV float bf2f(u16 h) { return __uint_as_float(((u32)h) << 16); }
DEV float siluf(float x) { return x / (1.f + __expf(-x)); }
DEV float geluf(float x) { return 0.5f * x * (1.f + erff(x * 0.70710678118654752f)); }

DEV void gload_lds16(const void* g, void* l) {
  __builtin_amdgcn_global_load_lds((const __attribute__((address_space(1))) void*)g,
                                   (__attribute__((address_space(3))) void*)l,
                                   16, 0, 0);
}

// compiler memory fence + hardware barrier (NO implicit vmcnt(0) drain)
#define BAR() do { asm volatile("" ::: "memory"); __builtin_amdgcn_s_barrier(); asm volatile("" ::: "memory"); } while (0)

// ---------------- converts ----------------
__global__ void cvtk(const float* __restrict__ in, u16* __restrict__ out, int n4, float scale) {
  int i = blockIdx.x * 256 + threadIdx.x;
  if (i >= n4) return;
  const float4 v = *(const float4*)(in + (size_t)i * 4);
  u16x4 o;
  o[0] = f2bf(v.x * scale); o[1] = f2bf(v.y * scale);
  o[2] = f2bf(v.z * scale); o[3] = f2bf(v.w * scale);
  *(u16x4*)(out + (size_t)i * 4) = o;
}

// conv_w [o][d][3] -> Wc [o][tap*1024 + d]
__global__ void cvt_convw(const float* __restrict__ cw, u16* __restrict__ Wc) {
  int i = blockIdx.x * 256 + threadIdx.x;   // 1M threads: o*1024+d
  int o = i >> 10, d = i & 1023;
  const float* src = cw + ((size_t)o * 1024 + d) * 3;
  u16* dst = Wc + (size_t)o * 3072 + d;
  dst[0]    = f2bf(src[0]);
  dst[1024] = f2bf(src[1]);
  dst[2048] = f2bf(src[2]);
}

// zero the 2 halo rows of each batch in Qpad
__global__ void zero_halo(u16* __restrict__ Qpad) {
  int i = blockIdx.x * 256 + threadIdx.x;   // 8192 threads
  int r = i >> 10, c = i & 1023;
  int b = r >> 1, side = r & 1;
  size_t row = (size_t)b * SPAD + (side ? (SPAD - 1) : 0);
  Qpad[row * 1024 + c] = 0;
}

// ---------------- GEMM: 256x128 tile, BK=64, 512 thr, 3-buf counted-vmcnt ----------------
// C[t,n] = sum_k A[t,k] * B[n,k]  (B row-major [N][K])
// MODE 0: bf16 out (+bias).  MODE 2: conv A-addressing, epilogue gelu(silu(v+b)).
// MODE 3: f32 out (+bias).   MODE 4: QOG fused, route by n>>10 (C/C2/C3, bias/bias2/bias3).
template<int MODE>
__global__ __launch_bounds__(512, 2)
void gemm_k(const u16* __restrict__ A, const u16* __restrict__ B,
            void* __restrict__ C, const float* __restrict__ bias,
            void* __restrict__ C2, void* __restrict__ C3,
            const float* __restrict__ bias2, const float* __restrict__ bias3,
            int M, int N, int K, int lda)
{
  __shared__ alignas(16) char smem[147456];   // 3 x (A 32KB + B 16KB)

  int nwg = gridDim.x;
  int bx = blockIdx.x;
  if ((nwg & 7) == 0) bx = (bx & 7) * (nwg >> 3) + (bx >> 3);  // XCD swizzle (bijective)
  int GN = N >> 7;                 // BN = 128
  int bm = bx / GN, bn = bx - bm * GN;
  int m0 = bm << 8, n0 = bn << 7;  // BM = 256

  int tid = threadIdx.x;           // 0..511 (8 waves)
  int lane = tid & 63, wid = tid >> 6;
  int wm = wid >> 1, wn = wid & 1; // 4 M-waves x 2 N-waves, wave out = 64x64

  int strow = tid >> 3;            // 0..63
  int stcolb = (tid & 7) << 4;     // byte col
  int sws = (strow & 7) << 4;      // stage-row swizzle (row&7 invariant under +64)
  size_t ldab = (size_t)lda * 2;
  size_t ldbb = (size_t)K * 2;
  int bofm = m0 >> 12;             // batch index of this m-tile (BM=256 never straddles 4096)

  // per-thread stage source offsets (bytes), LDS dest offsets
  size_t offA[4], offB[2];
#pragma unroll
  for (int j = 0; j < 4; ++j) offA[j] = (size_t)(j * 64 + strow) * ldab + (size_t)(stcolb ^ sws);
#pragma unroll
  for (int j = 0; j < 2; ++j) offB[j] = (size_t)(j * 64 + strow) * ldbb + (size_t)(stcolb ^ sws);
  int dstL[4];
#pragma unroll
  for (int j = 0; j < 4; ++j) dstL[j] = j * 8192 + wid * 1024;

  auto ABASE = [&](int tt) -> const char* {
    if (MODE == 2) {
      // tap = (tt*64)/1024, koff = (tt*64)%1024 ; halo-shifted Qpad rows
      return (const char*)(A + ((size_t)(m0 + 2 * bofm + (tt >> 4)) * (size_t)lda + ((tt & 15) << 6)));
    }
    return (const char*)(A + ((size_t)m0 * (size_t)lda + ((size_t)tt << 6)));
  };
  auto BBASE = [&](int tt) -> const char* {
    return (const char*)(B + ((size_t)n0 * (size_t)K + ((size_t)tt << 6)));
  };
  auto STAGE = [&](int tt, int p) {
    char* bufA = smem + (tt % 3) * 49152;
    char* bufB = bufA + 32768;
    const char* Ab = ABASE(tt);
    const char* Bb = BBASE(tt);
    if (p == 0) {
      gload_lds16(Ab + offA[0], bufA + dstL[0]);
      gload_lds16(Ab + offA[1], bufA + dstL[1]);
      gload_lds16(Bb + offB[0], bufB + dstL[0]);
    } else {
      gload_lds16(Ab + offA[2], bufA + dstL[2]);
      gload_lds16(Ab + offA[3], bufA + dstL[3]);
      gload_lds16(Bb + offB[1], bufB + dstL[1]);
    }
  };

  f32x4 acc[4][4] = {};
  const int KT = K >> 6;

  // prologue: tiles 0 and 1 in flight; wait for tile 0 (leave tile 1's 6 loads outstanding)
  STAGE(0, 0); STAGE(0, 1);
  STAGE(1, 0); STAGE(1, 1);
  asm volatile("s_waitcnt vmcnt(6)" ::: "memory");
  BAR();

  // fragment read offsets
  int ra[4], rbo[4];
#pragma unroll
  for (int i = 0; i < 4; ++i) ra[i] = ((wm << 6) + (i << 4) + (lane & 15)) * 128;
#pragma unroll
  for (int j = 0; j < 4; ++j) rbo[j] = ((wn << 6) + (j << 4) + (lane & 15)) * 128;
  int swr = (lane & 7) << 4;
  int cb0 = (lane >> 4) << 4;

  int c = 0;
  for (int t = 0; t < KT; ++t) {
    char* sAc = smem + c * 49152;
    char* sBc = sAc + 32768;
    bool pre = (t + 2 < KT);

    // ---- sub-phase 0 (kk = 0) ----
    {
      bf16x8 av[4], bv[4];
      int coff = cb0 ^ swr;
#pragma unroll
      for (int i = 0; i < 4; ++i) av[i] = *(const bf16x8*)(sAc + ra[i] + coff);
#pragma unroll
      for (int j = 0; j < 4; ++j) bv[j] = *(const bf16x8*)(sBc + rbo[j] + coff);
      if (pre) STAGE(t + 2, 0);
      BAR();
      __builtin_amdgcn_s_setprio(1);
#pragma unroll
      for (int i = 0; i < 4; ++i)
#pragma unroll
        for (int j = 0; j < 4; ++j)
          acc[i][j] = __builtin_amdgcn_mfma_f32_16x16x32_bf16(av[i], bv[j], acc[i][j], 0, 0, 0);
      __builtin_amdgcn_s_setprio(0);
      BAR();
    }
    // ---- sub-phase 1 (kk = 1) ----
    {
      bf16x8 av[4], bv[4];
      int coff = (cb0 + 64) ^ swr;
#pragma unroll
      for (int i = 0; i < 4; ++i) av[i] = *(const bf16x8*)(sAc + ra[i] + coff);
#pragma unroll
      for (int j = 0; j < 4; ++j) bv[j] = *(const bf16x8*)(sBc + rbo[j] + coff);
      if (pre) STAGE(t + 2, 1);
      BAR();
      __builtin_amdgcn_s_setprio(1);
#pragma unroll
      for (int i = 0; i < 4; ++i)
#pragma unroll
        for (int j = 0; j < 4; ++j)
          acc[i][j] = __builtin_amdgcn_mfma_f32_16x16x32_bf16(av[i], bv[j], acc[i][j], 0, 0, 0);
      __builtin_amdgcn_s_setprio(0);
      // tile-end: next tile (t+1) fully resident; only tile t+2's 6 loads may stay in flight
      if (pre) asm volatile("s_waitcnt vmcnt(6)" ::: "memory");
      else     asm volatile("s_waitcnt vmcnt(0)" ::: "memory");
      BAR();
    }
    c = (c == 2) ? 0 : c + 1;
  }

  // ---- epilogue ----
#pragma unroll
  for (int i = 0; i < 4; ++i) {
    int rb = m0 + (wm << 6) + (i << 4) + ((lane >> 4) << 2);
#pragma unroll
    for (int j = 0; j < 4; ++j) {
      int n = n0 + (wn << 6) + (j << 4) + (lane & 15);
      if (MODE == 4) {
        int seg = n >> 10, nn = n & 1023;
        const float* bsel = (seg == 0) ? bias : ((seg == 1) ? bias2 : bias3);
        float bs = bsel ? bsel[nn] : 0.f;
#pragma unroll
        for (int r = 0; r < 4; ++r) {
          int t = rb + r;
          u16 h = f2bf(acc[i][j][r] + bs);
          if (seg == 0) {
            size_t row = (size_t)t + 2 * (t >> 12) + 1;   // Q -> Qpad remap
            ((u16*)C)[row * 1024 + nn] = h;
          } else if (seg == 1) {
            ((u16*)C2)[(size_t)t * 1024 + nn] = h;
          } else {
            ((u16*)C3)[(size_t)t * 1024 + nn] = h;
          }
        }
      } else {
        float bs = bias ? bias[n] : 0.f;
#pragma unroll
        for (int r = 0; r < 4; ++r) {
          int t = rb + r;
          float v = acc[i][j][r] + bs;
          if (MODE == 0)      ((u16*)C)[(size_t)t * N + n] = f2bf(v);
          else if (MODE == 2) ((u16*)C)[(size_t)t * N + n] = f2bf(geluf(siluf(v)));
          else                ((float*)C)[(size_t)t * N + n] = v;
        }
      }
    }
  }
}

// ---------------- softmax-weighted column sum ----------------
__global__ void summ_partial(const u16* __restrict__ logits, const u16* __restrict__ vals,
                             float* __restrict__ pm, float* __restrict__ pz,
                             float* __restrict__ pn, int remap)
{
  int tid = threadIdx.x;
  int sc = blockIdx.x, ec = blockIdx.y, b = blockIdx.z;
  int e = ec * 256 + tid;
  float m = -1e30f, z = 0.f, num = 0.f;
  int t0 = b * 4096 + sc * 128;
  for (int si = 0; si < 128; ++si) {
    int t = t0 + si;
    float l = bf2f(logits[(size_t)t * 1024 + e]);
    size_t vrow = remap ? ((size_t)t + 2 * b + 1) : (size_t)t;
    float v = bf2f(vals[vrow * 1024 + e]);
    float mn = fmaxf(m, l);
    float cc = __expf(m - mn);
    float p = __expf(l - mn);
    z = z * cc + p;
    num = num * cc + v * p;
    m = mn;
  }
  int pidx = (((b * 4 + ec) * 32) + sc) * 256 + tid;
  pm[pidx] = m; pz[pidx] = z; pn[pidx] = num;
}

__global__ void summ_combine(const float* __restrict__ pm, const float* __restrict__ pz,
                             const float* __restrict__ pn, float* __restrict__ summ)
{
  int idx = blockIdx.x * 256 + threadIdx.x;  // 0..4095 : b*1024+e
  int b = idx >> 10, e = idx & 1023;
  int ec = e >> 8, tt = e & 255;
  const int base = ((b * 4 + ec) * 32) * 256 + tt;
  float M = -1e30f;
  for (int sc = 0; sc < 32; ++sc) M = fmaxf(M, pm[base + sc * 256]);
  float Z = 0.f, Nm = 0.f;
  for (int sc = 0; sc < 32; ++sc) {
    float w = __expf(pm[base + sc * 256] - M);
    Z += pz[base + sc * 256] * w;
    Nm += pn[base + sc * 256] * w;
  }
  summ[idx] = Nm / Z;
}

// ---------------- elementwise ----------------
__global__ void pk(const u16* __restrict__ O, const float* __restrict__ s1,
                   u16* __restrict__ P, u16* __restrict__ GP)
{
  size_t idx = (size_t)blockIdx.x * 256 + threadIdx.x;
  size_t base = idx * 8;
  int t = (int)(base >> 10);
  int b = t >> 12;
  int e = (int)(base & 1023);
  const float* sp = s1 + b * 1024 + e;
  u16x8 ov = *(const u16x8*)(O + base);
  u16x8 pv, gv;
#pragma unroll
  for (int j = 0; j < 8; ++j) {
    float p = bf2f(ov[j]) * sp[j];
    pv[j] = f2bf(p);
    gv[j] = f2bf(geluf(p));
  }
  *(u16x8*)(P + base) = pv;
  *(u16x8*)(GP + base) = gv;
}

__global__ void lk(const u16* __restrict__ G, const float* __restrict__ s2,
                   u16* __restrict__ L)
{
  size_t idx = (size_t)blockIdx.x * 256 + threadIdx.x;
  size_t base = idx * 8;
  int t = (int)(base >> 10);
  int b = t >> 12;
  int e = (int)(base & 1023);
  const float* sp = s2 + b * 1024 + e;
  u16x8 gvv = *(const u16x8*)(G + base);
  u16x8 lv;
#pragma unroll
  for (int j = 0; j < 8; ++j) {
    lv[j] = f2bf(siluf(bf2f(gvv[j])) * sp[j]);
  }
  *(u16x8*)(L + base) = lv;
}

// ---------------- launch ----------------
extern "C" void kernel_launch(void* const* d_in, const int* in_sizes, int n_in,
                              void* d_out, int out_size, void* d_ws, size_t ws_size,
                              hipStream_t stream)
{
  const float* x     = (const float*)d_in[0];
  const float* Wq    = (const float*)d_in[1];
  const float* Wqb   = (const float*)d_in[2];
  const float* Wo    = (const float*)d_in[3];
  const float* Wob   = (const float*)d_in[4];
  const float* Wg    = (const float*)d_in[5];
  const float* Wgb   = (const float*)d_in[6];
  const float* wa    = (const float*)d_in[7];
  const float* wb    = (const float*)d_in[8];
  const float* Wout  = (const float*)d_in[9];
  const float* Woutb = (const float*)d_in[10];
  const float* convw = (const float*)d_in[11];
  const float* convb = (const float*)d_in[12];

  char* ws = (char*)d_ws;
  size_t off = 0;
  auto alloc = [&](size_t bytes) -> char* {
    char* p = ws + off;
    off += (bytes + 255) & ~(size_t)255;
    return p;
  };

  u16* QPAD = (u16*)alloc((size_t)4 * SPAD * 1024 * 2);   // Qpad -> later P (plain layout)
  u16* OB   = (u16*)alloc((size_t)NT * 1024 * 2);         // O    -> later L
  u16* GB   = (u16*)alloc((size_t)NT * 1024 * 2);         // G
  u16* XB   = (u16*)alloc((size_t)NT * 1024 * 2);         // x_bf16 -> GA -> GP
  u16* SS   = (u16*)alloc((size_t)NT * 1024 * 2);         // logits A -> logits B
  u16* WQOG  = (u16*)alloc((size_t)3072 * 1024 * 2);      // [Wq;Wo;Wg]
  u16* WAB_  = (u16*)alloc((size_t)1024 * 1024 * 2);
  u16* WBB_  = (u16*)alloc((size_t)1024 * 1024 * 2);
  u16* WOUTB_= (u16*)alloc((size_t)1024 * 1024 * 2);
  u16* WCB_  = (u16*)alloc((size_t)1024 * 3072 * 2);
  float* PM = (float*)alloc((size_t)4 * 4 * 32 * 256 * 4);
  float* PZ = (float*)alloc((size_t)4 * 4 * 32 * 256 * 4);
  float* PN = (float*)alloc((size_t)4 * 4 * 32 * 256 * 4);
  float* S1 = (float*)alloc((size_t)4096 * 4);
  float* S2 = (float*)alloc((size_t)4096 * 4);

  if (off > ws_size) return;

  u16* PB = QPAD;  // P in plain [NT,1024] layout (Q dead by then)
  u16* GA = XB;
  u16* GP = XB;
  u16* LB = OB;

  const float scale = 0.03125f;  // 1/sqrt(1024)

  // 1. converts
  cvtk<<<16384, 256, 0, stream>>>(x, XB, 4194304, 1.0f);
  cvtk<<<1024, 256, 0, stream>>>(Wq, WQOG,            262144, 1.0f);
  cvtk<<<1024, 256, 0, stream>>>(Wo, WQOG + 1048576,  262144, 1.0f);
  cvtk<<<1024, 256, 0, stream>>>(Wg, WQOG + 2097152,  262144, 1.0f);
  cvtk<<<1024, 256, 0, stream>>>(wa, WAB_, 262144, scale);
  cvtk<<<1024, 256, 0, stream>>>(wb, WBB_, 262144, scale);
  cvtk<<<1024, 256, 0, stream>>>(Wout, WOUTB_, 262144, 1.0f);
  cvt_convw<<<4096, 256, 0, stream>>>(convw, WCB_);
  zero_halo<<<32, 256, 0, stream>>>(QPAD);

  // 2. fused Q/O/G GEMM: N=3072, routed epilogue
  gemm_k<4><<<64 * 24, 512, 0, stream>>>(XB, WQOG, QPAD, Wqb, OB, GB, Wob, Wgb,
                                         NT, 3072, 1024, 1024);

  // 3. conv as GEMM (A = Qpad, K = 3072), epilogue gelu(silu(.)) -> GA
  gemm_k<2><<<64 * 8, 512, 0, stream>>>(QPAD, WCB_, GA, convb, nullptr, nullptr, nullptr, nullptr,
                                        NT, 1024, 3072, 1024);

  // 4. logits A = GA @ (wa*scale)^T -> SS
  gemm_k<0><<<64 * 8, 512, 0, stream>>>(GA, WAB_, SS, nullptr, nullptr, nullptr, nullptr, nullptr,
                                        NT, 1024, 1024, 1024);

  // 5. summ1 = softmax-weighted sum of Q
  {
    dim3 g(32, 4, 4);
    summ_partial<<<g, 256, 0, stream>>>(SS, QPAD, PM, PZ, PN, 1);
    summ_combine<<<16, 256, 0, stream>>>(PM, PZ, PN, S1);
  }

  // 6. P = O * summ1 ; GP = gelu(P)
  pk<<<8192, 256, 0, stream>>>(OB, S1, PB, GP);

  // 7. logits B = GP @ (wb*scale)^T -> SS
  gemm_k<0><<<64 * 8, 512, 0, stream>>>(GP, WBB_, SS, nullptr, nullptr, nullptr, nullptr, nullptr,
                                        NT, 1024, 1024, 1024);

  // 8. summ2 = softmax-weighted sum of P
  {
    dim3 g(32, 4, 4);
    summ_partial<<<g, 256, 0, stream>>>(SS, PB, PM, PZ, PN, 0);
    summ_combine<<<16, 256, 0, stream>>>(PM, PZ, PN, S2);
  }

  // 9. L = silu(G) * summ2
  lk<<<8192, 256, 0, stream>>>(GB, S2, LB);

  // 10. out = L @ Wout^T + b  (fp32)
  gemm_k<3><<<64 * 8, 512, 0, stream>>>(LB, WOUTB_, d_out, Woutb, nullptr, nullptr, nullptr, nullptr,
                                        NT, 1024, 1024, 1024);
}

// Round 3
// 544.420 us; speedup vs baseline: 1.0077x; 1.0077x over previous
//
#include <hip/hip_runtime.h>
#include <stdint.h>

#define DEV __device__ __forceinline__

typedef unsigned short u16;
typedef unsigned int u32;

typedef __bf16 bf16x8 __attribute__((ext_vector_type(8)));
typedef float f32x4 __attribute__((ext_vector_type(4)));
typedef u16 u16x8 __attribute__((ext_vector_type(8)));
typedef u16 u16x4 __attribute__((ext_vector_type(4)));

static_assert(sizeof(bf16x8) == 16, "bf16x8 must be 16B");

#define NT 16384      // B*S = 4*4096
#define SPAD 4098     // S + 2 halo rows per batch

DEV u16 f2bf(float f) {
  u32 u = __float_as_uint(f);
  u32 r = u + 0x7FFFu + ((u >> 16) & 1u);
  return (u16)(r >> 16);
}
DEV float bf2f(u16 h) { return __uint_as_float(((u32)h) << 16); }
DEV float siluf(float x) { return x / (1.f + __expf(-x)); }
DEV float geluf(float x) { return 0.5f * x * (1.f + erff(x * 0.70710678118654752f)); }

DEV void gload_lds16(const void* g, void* l) {
  __builtin_amdgcn_global_load_lds((const __attribute__((address_space(1))) void*)g,
                                   (__attribute__((address_space(3))) void*)l,
                                   16, 0, 0);
}

// ---------------- converts ----------------
__global__ void cvtk(const float* __restrict__ in, u16* __restrict__ out, int n4, float scale) {
  int i = blockIdx.x * 256 + threadIdx.x;
  if (i >= n4) return;
  const float4 v = *(const float4*)(in + (size_t)i * 4);
  u16x4 o;
  o[0] = f2bf(v.x * scale); o[1] = f2bf(v.y * scale);
  o[2] = f2bf(v.z * scale); o[3] = f2bf(v.w * scale);
  *(u16x4*)(out + (size_t)i * 4) = o;
}

// 6 d*d weight matrices -> one contiguous bf16 buffer [Wq,Wo,Wg,wa*s,wb*s,Wout]
__global__ void cvtw6(const float* __restrict__ w0, const float* __restrict__ w1,
                      const float* __restrict__ w2, const float* __restrict__ w3,
                      const float* __restrict__ w4, const float* __restrict__ w5,
                      u16* __restrict__ dst, float s) {
  int idx = blockIdx.x * 256 + threadIdx.x;      // 6 * 262144 four-elem groups
  int mat = idx >> 18, within = idx & 262143;
  const float* src; float sc = 1.0f;
  if (mat == 0) src = w0;
  else if (mat == 1) src = w1;
  else if (mat == 2) src = w2;
  else if (mat == 3) { src = w3; sc = s; }
  else if (mat == 4) { src = w4; sc = s; }
  else src = w5;
  const float4 v = *(const float4*)(src + (size_t)within * 4);
  u16x4 o;
  o[0] = f2bf(v.x * sc); o[1] = f2bf(v.y * sc);
  o[2] = f2bf(v.z * sc); o[3] = f2bf(v.w * sc);
  *(u16x4*)(dst + (size_t)idx * 4) = o;
}

// conv_w [o][d][3] -> Wc [o][tap*1024 + d]
__global__ void cvt_convw(const float* __restrict__ cw, u16* __restrict__ Wc) {
  int i = blockIdx.x * 256 + threadIdx.x;   // 1M threads: o*1024+d
  int o = i >> 10, d = i & 1023;
  const float* src = cw + ((size_t)o * 1024 + d) * 3;
  u16* dst = Wc + (size_t)o * 3072 + d;
  dst[0]    = f2bf(src[0]);
  dst[1024] = f2bf(src[1]);
  dst[2048] = f2bf(src[2]);
}

// zero the 2 halo rows of each batch in Qpad
__global__ void zero_halo(u16* __restrict__ Qpad) {
  int i = blockIdx.x * 256 + threadIdx.x;   // 8192 threads
  int r = i >> 10, c = i & 1023;
  int b = r >> 1, side = r & 1;
  size_t row = (size_t)b * SPAD + (side ? (SPAD - 1) : 0);
  Qpad[row * 1024 + c] = 0;
}

// ---------------- GEMM: 256x256 tile, BK=64, 512 thr, 4-phase counted-vmcnt ----------------
// C[t,n] = sum_k A[t,k] * B[n,k]  (B row-major [N][K])
// MODE 0: bf16 out (+bias). MODE 2: conv A-addressing (A=Qpad), epilogue gelu(silu(v+b)).
// MODE 3: f32 out (+bias). MODE 4: QOG fused, route by n>>10; Q remapped into Qpad.
template<int MODE>
__global__ __launch_bounds__(512, 1)
void gemm256(const u16* __restrict__ A, const u16* __restrict__ B,
             void* __restrict__ C, const float* __restrict__ bias,
             void* __restrict__ C2, void* __restrict__ C3,
             const float* __restrict__ bias2, const float* __restrict__ bias3,
             int M, int N, int K, int lda)
{
  // buf t: +(t&1)*65536 ; A 32KB then B 32KB ; dummy region at 131072
  __shared__ alignas(16) char smem[132096];

  int nwg = gridDim.x;
  int bx = blockIdx.x;
  if ((nwg & 7) == 0) bx = (bx & 7) * (nwg >> 3) + (bx >> 3);  // XCD swizzle (bijective)
  int GN = N >> 8;                 // BN = 256
  int bm = bx / GN, bn = bx - bm * GN;
  int m0 = bm << 8, n0 = bn << 8;  // BM = 256

  int tid = threadIdx.x;           // 512 threads = 8 waves
  int lane = tid & 63, wid = tid >> 6;
  int wm = wid >> 2, wn = wid & 3; // wave out: rows [wm*128,+128), cols [wn*64,+64)

  int l3 = lane >> 3, l7 = lane & 7;
  int scol = ((l7 ^ l3) << 4);                 // pre-swizzled source col within 128B row
  size_t ldab = (size_t)lda * 2;
  size_t ldbb = (size_t)K * 2;
  size_t plA = (size_t)l3 * ldab + scol;       // per-thread source delta (A stages)
  size_t plB = (size_t)l3 * ldbb + scol;
  int bofm = m0 >> 12;                         // batch of this m-tile (256 | 4096)
  int brow0w = ((wid & 3) << 3) + ((wid >> 2) << 6);  // B-stage wave row base pattern

  // fragment read offsets (bytes)
  int rowA0 = (wm * 128 + (lane & 15)) * 128;
  int rowB0 = (wn * 64 + (lane & 15)) * 128;
  int col0 = (((lane >> 4) << 4)) ^ (l7 << 4);
  int col1 = (((lane >> 4) << 4) + 64) ^ (l7 << 4);

  const int KT = K >> 6;

  // stage chunk A_m (rows {m*64..+63} U {128+m*64..+63}) of K-tile tt into buf
  auto stageA = [&](int tt, int m, int buf) {
    char* dst = smem + buf * 65536 + (m * 64 + wid * 8) * 128;
    const char* src;
    if (MODE == 2)
      src = (const char*)A + (size_t)(m0 + 2 * bofm + (tt >> 4) + m * 64 + wid * 8) * ldab + ((size_t)(tt & 15) << 7);
    else
      src = (const char*)A + (size_t)(m0 + m * 64 + wid * 8) * ldab + ((size_t)tt << 7);
    gload_lds16(src + plA, dst);
    gload_lds16(src + (size_t)128 * ldab + plA, dst + 16384);
  };
  // stage chunk B_n (rows == [n*32,(n+1)*32) mod 64) of K-tile tt into buf
  auto stageB = [&](int tt, int n, int buf) {
    char* dst = smem + buf * 65536 + 32768 + (n * 32 + brow0w) * 128;
    const char* src = (const char*)B + (size_t)(n0 + n * 32 + brow0w) * ldbb + ((size_t)tt << 7);
    gload_lds16(src + plB, dst);
    gload_lds16(src + (size_t)128 * ldbb + plB, dst + 16384);
  };
  auto stageDummy = [&]() {   // keeps vmcnt bookkeeping exact in the K-tail
    gload_lds16((const char*)A + plA, smem + 131072);
    gload_lds16((const char*)A + plA, smem + 131072);
  };

  f32x4 acc[8][4] = {};

  // prologue: A0(0),B1(0),A1(0),B0(0),A0(1),B1(1)  (order matters for vmcnt counts)
  stageA(0, 0, 0); stageB(0, 1, 0); stageA(0, 1, 0); stageB(0, 0, 0);
  stageA(1, 0, 1); stageB(1, 1, 1);

#define PHASE(MQ, NQ, VMN, ...) do {                                          \
    asm volatile("s_waitcnt vmcnt(" VMN ")" ::: "memory");                    \
    __builtin_amdgcn_s_barrier();                                             \
    char* bA = smem + cu * 65536;                                             \
    char* bB = bA + 32768;                                                    \
    bf16x8 avv[4][2], bvv[2][2];                                              \
    _Pragma("unroll")                                                         \
    for (int i = 0; i < 4; ++i) {                                             \
      avv[i][0] = *(const bf16x8*)(bA + rowA0 + ((MQ)*4 + i) * 2048 + col0);  \
      avv[i][1] = *(const bf16x8*)(bA + rowA0 + ((MQ)*4 + i) * 2048 + col1);  \
    }                                                                         \
    _Pragma("unroll")                                                         \
    for (int j = 0; j < 2; ++j) {                                             \
      bvv[j][0] = *(const bf16x8*)(bB + rowB0 + ((NQ)*2 + j) * 2048 + col0);  \
      bvv[j][1] = *(const bf16x8*)(bB + rowB0 + ((NQ)*2 + j) * 2048 + col1);  \
    }                                                                         \
    __VA_ARGS__;                                                              \
    __builtin_amdgcn_s_barrier();                                             \
    asm volatile("s_waitcnt lgkmcnt(0)" ::: "memory");                        \
    __builtin_amdgcn_sched_barrier(0);                                        \
    __builtin_amdgcn_s_setprio(1);                                            \
    _Pragma("unroll")                                                         \
    for (int i = 0; i < 4; ++i)                                               \
      _Pragma("unroll")                                                       \
      for (int j = 0; j < 2; ++j) {                                           \
        acc[(MQ)*4 + i][(NQ)*2 + j] =                                         \
          __builtin_amdgcn_mfma_f32_16x16x32_bf16(avv[i][0], bvv[j][0],       \
                                                  acc[(MQ)*4 + i][(NQ)*2 + j], 0, 0, 0); \
        acc[(MQ)*4 + i][(NQ)*2 + j] =                                         \
          __builtin_amdgcn_mfma_f32_16x16x32_bf16(avv[i][1], bvv[j][1],       \
                                                  acc[(MQ)*4 + i][(NQ)*2 + j], 0, 0, 0); \
      }                                                                       \
    __builtin_amdgcn_s_setprio(0);                                            \
    __builtin_amdgcn_sched_barrier(0);                                        \
  } while (0)

  for (int t = 0; t < KT; ++t) {
    int cu = t & 1;
    // P0 (Mlo,Nlo): stage A-hi of tile t+1 (other buffer)
    PHASE(0, 0, "4",  if (t + 1 < KT) stageA(t + 1, 1, cu ^ 1); else stageDummy(); );
    // P1 (Mlo,Nhi): stage B-lo of tile t+1 (other buffer)
    PHASE(0, 1, "10", if (t + 1 < KT) stageB(t + 1, 0, cu ^ 1); else stageDummy(); );
    // P2 (Mhi,Nhi): stage A-lo of tile t+2 (own buffer; A-lo free after P1)
    PHASE(1, 1, "10", if (t + 2 < KT) stageA(t + 2, 0, cu); else stageDummy(); );
    // P3 (Mhi,Nlo): stage B-hi of tile t+2 (own buffer; B-hi free after P2)
    PHASE(1, 0, "10", if (t + 2 < KT) stageB(t + 2, 1, cu); else stageDummy(); );
  }
#undef PHASE

  asm volatile("s_waitcnt vmcnt(0)" ::: "memory");   // drain dummy stages before exit

  // ---- epilogue: frag row=(lane>>4)*4+r, col=lane&15 ----
#pragma unroll
  for (int i = 0; i < 8; ++i) {
    int rb = m0 + wm * 128 + i * 16 + ((lane >> 4) << 2);
#pragma unroll
    for (int j = 0; j < 4; ++j) {
      int n = n0 + wn * 64 + j * 16 + (lane & 15);
      if (MODE == 4) {
        int seg = n >> 10, nn = n & 1023;
        const float* bsel = (seg == 0) ? bias : ((seg == 1) ? bias2 : bias3);
        float bs = bsel ? bsel[nn] : 0.f;
#pragma unroll
        for (int r = 0; r < 4; ++r) {
          int t = rb + r;
          u16 h = f2bf(acc[i][j][r] + bs);
          if (seg == 0) {
            size_t row = (size_t)t + 2 * (t >> 12) + 1;   // Q -> Qpad remap
            ((u16*)C)[row * 1024 + nn] = h;
          } else if (seg == 1) {
            ((u16*)C2)[(size_t)t * 1024 + nn] = h;
          } else {
            ((u16*)C3)[(size_t)t * 1024 + nn] = h;
          }
        }
      } else {
        float bs = bias ? bias[n] : 0.f;
#pragma unroll
        for (int r = 0; r < 4; ++r) {
          int t = rb + r;
          float v = acc[i][j][r] + bs;
          if (MODE == 0)      ((u16*)C)[(size_t)t * N + n] = f2bf(v);
          else if (MODE == 2) ((u16*)C)[(size_t)t * N + n] = f2bf(geluf(siluf(v)));
          else                ((float*)C)[(size_t)t * N + n] = v;
        }
      }
    }
  }
}

// ---------------- softmax-weighted column sum ----------------
__global__ void summ_partial(const u16* __restrict__ logits, const u16* __restrict__ vals,
                             float* __restrict__ pm, float* __restrict__ pz,
                             float* __restrict__ pn, int remap)
{
  int tid = threadIdx.x;
  int sc = blockIdx.x, ec = blockIdx.y, b = blockIdx.z;
  int e = ec * 256 + tid;
  float m = -1e30f, z = 0.f, num = 0.f;
  int t0 = b * 4096 + sc * 128;
  for (int si = 0; si < 128; ++si) {
    int t = t0 + si;
    float l = bf2f(logits[(size_t)t * 1024 + e]);
    size_t vrow = remap ? ((size_t)t + 2 * b + 1) : (size_t)t;
    float v = bf2f(vals[vrow * 1024 + e]);
    float mn = fmaxf(m, l);
    float cc = __expf(m - mn);
    float p = __expf(l - mn);
    z = z * cc + p;
    num = num * cc + v * p;
    m = mn;
  }
  int pidx = (((b * 4 + ec) * 32) + sc) * 256 + tid;
  pm[pidx] = m; pz[pidx] = z; pn[pidx] = num;
}

__global__ void summ_combine(const float* __restrict__ pm, const float* __restrict__ pz,
                             const float* __restrict__ pn, float* __restrict__ summ)
{
  int idx = blockIdx.x * 256 + threadIdx.x;  // 0..4095 : b*1024+e
  int b = idx >> 10, e = idx & 1023;
  int ec = e >> 8, tt = e & 255;
  const int base = ((b * 4 + ec) * 32) * 256 + tt;
  float M = -1e30f;
  for (int sc = 0; sc < 32; ++sc) M = fmaxf(M, pm[base + sc * 256]);
  float Z = 0.f, Nm = 0.f;
  for (int sc = 0; sc < 32; ++sc) {
    float w = __expf(pm[base + sc * 256] - M);
    Z += pz[base + sc * 256] * w;
    Nm += pn[base + sc * 256] * w;
  }
  summ[idx] = Nm / Z;
}

// ---------------- elementwise ----------------
__global__ void pk(const u16* __restrict__ O, const float* __restrict__ s1,
                   u16* __restrict__ P, u16* __restrict__ GP)
{
  size_t idx = (size_t)blockIdx.x * 256 + threadIdx.x;
  size_t base = idx * 8;
  int t = (int)(base >> 10);
  int b = t >> 12;
  int e = (int)(base & 1023);
  const float* sp = s1 + b * 1024 + e;
  u16x8 ov = *(const u16x8*)(O + base);
  u16x8 pv, gv;
#pragma unroll
  for (int j = 0; j < 8; ++j) {
    float p = bf2f(ov[j]) * sp[j];
    pv[j] = f2bf(p);
    gv[j] = f2bf(geluf(p));
  }
  *(u16x8*)(P + base) = pv;
  *(u16x8*)(GP + base) = gv;
}

__global__ void lk(const u16* __restrict__ G, const float* __restrict__ s2,
                   u16* __restrict__ L)
{
  size_t idx = (size_t)blockIdx.x * 256 + threadIdx.x;
  size_t base = idx * 8;
  int t = (int)(base >> 10);
  int b = t >> 12;
  int e = (int)(base & 1023);
  const float* sp = s2 + b * 1024 + e;
  u16x8 gvv = *(const u16x8*)(G + base);
  u16x8 lv;
#pragma unroll
  for (int j = 0; j < 8; ++j) {
    lv[j] = f2bf(siluf(bf2f(gvv[j])) * sp[j]);
  }
  *(u16x8*)(L + base) = lv;
}

// ---------------- launch ----------------
extern "C" void kernel_launch(void* const* d_in, const int* in_sizes, int n_in,
                              void* d_out, int out_size, void* d_ws, size_t ws_size,
                              hipStream_t stream)
{
  const float* x     = (const float*)d_in[0];
  const float* Wq    = (const float*)d_in[1];
  const float* Wqb   = (const float*)d_in[2];
  const float* Wo    = (const float*)d_in[3];
  const float* Wob   = (const float*)d_in[4];
  const float* Wg    = (const float*)d_in[5];
  const float* Wgb   = (const float*)d_in[6];
  const float* wa    = (const float*)d_in[7];
  const float* wb    = (const float*)d_in[8];
  const float* Wout  = (const float*)d_in[9];
  const float* Woutb = (const float*)d_in[10];
  const float* convw = (const float*)d_in[11];
  const float* convb = (const float*)d_in[12];

  char* ws = (char*)d_ws;
  size_t off = 0;
  auto alloc = [&](size_t bytes) -> char* {
    char* p = ws + off;
    off += (bytes + 255) & ~(size_t)255;
    return p;
  };

  u16* QPAD = (u16*)alloc((size_t)4 * SPAD * 1024 * 2);   // Qpad -> later P (plain layout)
  u16* OB   = (u16*)alloc((size_t)NT * 1024 * 2);         // O    -> later L
  u16* GB   = (u16*)alloc((size_t)NT * 1024 * 2);         // G
  u16* XB   = (u16*)alloc((size_t)NT * 1024 * 2);         // x_bf16 -> GA -> GP
  u16* SS   = (u16*)alloc((size_t)NT * 1024 * 2);         // logits A -> logits B
  u16* WALL = (u16*)alloc((size_t)6 * 1024 * 1024 * 2);   // [Wq,Wo,Wg,wa*s,wb*s,Wout]
  u16* WCB_ = (u16*)alloc((size_t)1024 * 3072 * 2);
  float* PM = (float*)alloc((size_t)4 * 4 * 32 * 256 * 4);
  float* PZ = (float*)alloc((size_t)4 * 4 * 32 * 256 * 4);
  float* PN = (float*)alloc((size_t)4 * 4 * 32 * 256 * 4);
  float* S1 = (float*)alloc((size_t)4096 * 4);
  float* S2 = (float*)alloc((size_t)4096 * 4);

  if (off > ws_size) return;

  u16* WQOG   = WALL;
  u16* WAB_   = WALL + (size_t)3 * 1048576;
  u16* WBB_   = WALL + (size_t)4 * 1048576;
  u16* WOUTB_ = WALL + (size_t)5 * 1048576;

  u16* PB = QPAD;  // P in plain [NT,1024] layout (Q dead by then)
  u16* GA = XB;
  u16* GP = XB;
  u16* LB = OB;

  const float scale = 0.03125f;  // 1/sqrt(1024)

  // 1. converts
  cvtk<<<16384, 256, 0, stream>>>(x, XB, 4194304, 1.0f);
  cvtw6<<<6144, 256, 0, stream>>>(Wq, Wo, Wg, wa, wb, Wout, WALL, scale);
  cvt_convw<<<4096, 256, 0, stream>>>(convw, WCB_);
  zero_halo<<<32, 256, 0, stream>>>(QPAD);

  // 2. fused Q/O/G GEMM: N=3072, routed epilogue (Q remapped into QPAD)
  gemm256<4><<<64 * 12, 512, 0, stream>>>(XB, WQOG, QPAD, Wqb, OB, GB, Wob, Wgb,
                                          NT, 3072, 1024, 1024);

  // 3. conv as GEMM (A = Qpad, K = 3072), epilogue gelu(silu(.)) -> GA
  gemm256<2><<<64 * 4, 512, 0, stream>>>(QPAD, WCB_, GA, convb, nullptr, nullptr, nullptr, nullptr,
                                         NT, 1024, 3072, 1024);

  // 4. logits A = GA @ (wa*scale)^T -> SS
  gemm256<0><<<64 * 4, 512, 0, stream>>>(GA, WAB_, SS, nullptr, nullptr, nullptr, nullptr, nullptr,
                                         NT, 1024, 1024, 1024);

  // 5. summ1 = softmax-weighted sum of Q
  {
    dim3 g(32, 4, 4);
    summ_partial<<<g, 256, 0, stream>>>(SS, QPAD, PM, PZ, PN, 1);
    summ_combine<<<16, 256, 0, stream>>>(PM, PZ, PN, S1);
  }

  // 6. P = O * summ1 ; GP = gelu(P)
  pk<<<8192, 256, 0, stream>>>(OB, S1, PB, GP);

  // 7. logits B = GP @ (wb*scale)^T -> SS
  gemm256<0><<<64 * 4, 512, 0, stream>>>(GP, WBB_, SS, nullptr, nullptr, nullptr, nullptr, nullptr,
                                         NT, 1024, 1024, 1024);

  // 8. summ2 = softmax-weighted sum of P
  {
    dim3 g(32, 4, 4);
    summ_partial<<<g, 256, 0, stream>>>(SS, PB, PM, PZ, PN, 0);
    summ_combine<<<16, 256, 0, stream>>>(PM, PZ, PN, S2);
  }

  // 9. L = silu(G) * summ2
  lk<<<8192, 256, 0, stream>>>(GB, S2, LB);

  // 10. out = L @ Wout^T + b  (fp32)
  gemm256<3><<<64 * 4, 512, 0, stream>>>(LB, WOUTB_, d_out, Woutb, nullptr, nullptr, nullptr, nullptr,
                                         NT, 1024, 1024, 1024);
}

// Round 4
// 487.092 us; speedup vs baseline: 1.1263x; 1.1177x over previous
//
#include <hip/hip_runtime.h>
#include <stdint.h>

#define DEV __device__ __forceinline__

typedef unsigned short u16;
typedef unsigned int u32;

typedef __bf16 bf16x8 __attribute__((ext_vector_type(8)));
typedef float f32x4 __attribute__((ext_vector_type(4)));
typedef u16 u16x8 __attribute__((ext_vector_type(8)));
typedef u16 u16x4 __attribute__((ext_vector_type(4)));

static_assert(sizeof(bf16x8) == 16, "bf16x8 must be 16B");

#define NT 16384      // B*S = 4*4096
#define SPAD 4098     // S + 2 halo rows per batch

DEV u16 f2bf(float f) {
  u32 u = __float_as_uint(f);
  u32 r = u + 0x7FFFu + ((u >> 16) & 1u);
  return (u16)(r >> 16);
}
DEV float bf2f(u16 h) { return __uint_as_float(((u32)h) << 16); }
DEV float siluf(float x) { return x / (1.f + __expf(-x)); }
DEV float geluf(float x) { return 0.5f * x * (1.f + erff(x * 0.70710678118654752f)); }

DEV void gload_lds16(const void* g, void* l) {
  __builtin_amdgcn_global_load_lds((const __attribute__((address_space(1))) void*)g,
                                   (__attribute__((address_space(3))) void*)l,
                                   16, 0, 0);
}

// ---------------- converts ----------------
__global__ void cvtk(const float* __restrict__ in, u16* __restrict__ out, int n4, float scale) {
  int i = blockIdx.x * 256 + threadIdx.x;
  if (i >= n4) return;
  const float4 v = *(const float4*)(in + (size_t)i * 4);
  u16x4 o;
  o[0] = f2bf(v.x * scale); o[1] = f2bf(v.y * scale);
  o[2] = f2bf(v.z * scale); o[3] = f2bf(v.w * scale);
  *(u16x4*)(out + (size_t)i * 4) = o;
}

// 6 d*d weight matrices -> one contiguous bf16 buffer [Wq,Wo,Wg,wa*s,wb*s,Wout]
__global__ void cvtw6(const float* __restrict__ w0, const float* __restrict__ w1,
                      const float* __restrict__ w2, const float* __restrict__ w3,
                      const float* __restrict__ w4, const float* __restrict__ w5,
                      u16* __restrict__ dst, float s) {
  int idx = blockIdx.x * 256 + threadIdx.x;      // 6 * 262144 four-elem groups
  int mat = idx >> 18, within = idx & 262143;
  const float* src; float sc = 1.0f;
  if (mat == 0) src = w0;
  else if (mat == 1) src = w1;
  else if (mat == 2) src = w2;
  else if (mat == 3) { src = w3; sc = s; }
  else if (mat == 4) { src = w4; sc = s; }
  else src = w5;
  const float4 v = *(const float4*)(src + (size_t)within * 4);
  u16x4 o;
  o[0] = f2bf(v.x * sc); o[1] = f2bf(v.y * sc);
  o[2] = f2bf(v.z * sc); o[3] = f2bf(v.w * sc);
  *(u16x4*)(dst + (size_t)idx * 4) = o;
}

// conv_w [o][d][3] -> Wc [o][tap*1024 + d]
__global__ void cvt_convw(const float* __restrict__ cw, u16* __restrict__ Wc) {
  int i = blockIdx.x * 256 + threadIdx.x;   // 1M threads: o*1024+d
  int o = i >> 10, d = i & 1023;
  const float* src = cw + ((size_t)o * 1024 + d) * 3;
  u16* dst = Wc + (size_t)o * 3072 + d;
  dst[0]    = f2bf(src[0]);
  dst[1024] = f2bf(src[1]);
  dst[2048] = f2bf(src[2]);
}

// zero the 2 halo rows of each batch in Qpad
__global__ void zero_halo(u16* __restrict__ Qpad) {
  int i = blockIdx.x * 256 + threadIdx.x;   // 8192 threads
  int r = i >> 10, c = i & 1023;
  int b = r >> 1, side = r & 1;
  size_t row = (size_t)b * SPAD + (side ? (SPAD - 1) : 0);
  Qpad[row * 1024 + c] = 0;
}

// ================= gemm128: PROVEN round-1 structure (888 TF) =================
// 128x128 tile, BK=64, 256 thr, single-buffer LDS + syncthreads drain.
// MODE 0: bf16 out (+bias). MODE 2: conv A-addressing, epilogue gelu(silu(v+b)).
// MODE 3: f32 out. MODE 4: QOG fused, seg = n>>10 (block-uniform), Q->Qpad remap.
template<int MODE>
__global__ __launch_bounds__(256, 2)
void gemm128(const u16* __restrict__ A, const u16* __restrict__ B,
             void* __restrict__ C, const float* __restrict__ bias,
             void* __restrict__ C2, void* __restrict__ C3,
             const float* __restrict__ bias2, const float* __restrict__ bias3,
             int M, int N, int K, int lda)
{
  __shared__ alignas(16) char smem[32768];
  char* sA = smem;
  char* sB = smem + 16384;

  int nwg = gridDim.x;
  int bx = blockIdx.x;
  if ((nwg & 7) == 0) bx = (bx & 7) * (nwg >> 3) + (bx >> 3);  // XCD swizzle (bijective)
  int GN = N >> 7;
  int bm = bx / GN, bn = bx - bm * GN;
  int m0 = bm << 7, n0 = bn << 7;

  int tid = threadIdx.x;
  int lane = tid & 63, wid = tid >> 6;
  int wm = wid >> 1, wn = wid & 1;

  f32x4 acc[4][4] = {};

  int strow = tid >> 3;            // 0..31
  int stcolb = (tid & 7) << 4;     // byte col 0..112
  size_t ldab = (size_t)lda * 2;
  size_t ldbb = (size_t)K * 2;
  int bofm = m0 >> 12;             // batch of this m-tile (tiles never straddle batches)

  const int KT = K >> 6;
  for (int kt = 0; kt < KT; ++kt) {
    int k0 = kt << 6;
    const char* Ab;
    if (MODE == 2) {
      int tap = k0 >> 10;
      Ab = (const char*)(A + ((size_t)(m0 + 2 * bofm + tap) * (size_t)lda + (k0 & 1023)));
    } else {
      Ab = (const char*)(A + ((size_t)m0 * (size_t)lda + k0));
    }
    const char* Bb = (const char*)(B + ((size_t)n0 * (size_t)K + k0));
#pragma unroll
    for (int j = 0; j < 4; ++j) {
      int row = j * 32 + strow;
      int sw = (row & 7) << 4;     // XOR swizzle on 16B granules (involution)
      gload_lds16(Ab + (size_t)row * ldab + (size_t)(stcolb ^ sw), sA + j * 4096 + wid * 1024);
      gload_lds16(Bb + (size_t)row * ldbb + (size_t)(stcolb ^ sw), sB + j * 4096 + wid * 1024);
    }
    __syncthreads();
#pragma unroll
    for (int kk = 0; kk < 2; ++kk) {
      bf16x8 av[4], bv[4];
      int cb = ((lane >> 4) << 4) + (kk << 6);
#pragma unroll
      for (int i = 0; i < 4; ++i) {
        int r = (wm << 6) + (i << 4) + (lane & 15);
        av[i] = *(const bf16x8*)(sA + r * 128 + (cb ^ ((r & 7) << 4)));
      }
#pragma unroll
      for (int j = 0; j < 4; ++j) {
        int r = (wn << 6) + (j << 4) + (lane & 15);
        bv[j] = *(const bf16x8*)(sB + r * 128 + (cb ^ ((r & 7) << 4)));
      }
#pragma unroll
      for (int i = 0; i < 4; ++i)
#pragma unroll
        for (int j = 0; j < 4; ++j)
          acc[i][j] = __builtin_amdgcn_mfma_f32_16x16x32_bf16(av[i], bv[j], acc[i][j], 0, 0, 0);
    }
    __syncthreads();
  }

  // epilogue: frag row=(lane>>4)*4+r, col=lane&15
#pragma unroll
  for (int i = 0; i < 4; ++i) {
    int rb = m0 + (wm << 6) + (i << 4) + ((lane >> 4) << 2);
#pragma unroll
    for (int j = 0; j < 4; ++j) {
      int n = n0 + (wn << 6) + (j << 4) + (lane & 15);
      if (MODE == 4) {
        int seg = n >> 10, nn = n & 1023;    // seg is block-uniform (128 | 1024)
        const float* bsel = (seg == 0) ? bias : ((seg == 1) ? bias2 : bias3);
        float bs = bsel ? bsel[nn] : 0.f;
#pragma unroll
        for (int r = 0; r < 4; ++r) {
          int t = rb + r;
          u16 h = f2bf(acc[i][j][r] + bs);
          if (seg == 0) {
            size_t row = (size_t)t + 2 * (t >> 12) + 1;   // Q -> Qpad remap
            ((u16*)C)[row * 1024 + nn] = h;
          } else if (seg == 1) {
            ((u16*)C2)[(size_t)t * 1024 + nn] = h;
          } else {
            ((u16*)C3)[(size_t)t * 1024 + nn] = h;
          }
        }
      } else {
        float bs = bias ? bias[n] : 0.f;
#pragma unroll
        for (int r = 0; r < 4; ++r) {
          int t = rb + r;
          float v = acc[i][j][r] + bs;
          if (MODE == 0)      ((u16*)C)[(size_t)t * N + n] = f2bf(v);
          else if (MODE == 2) ((u16*)C)[(size_t)t * N + n] = f2bf(geluf(siluf(v)));
          else                ((float*)C)[(size_t)t * N + n] = v;
        }
      }
    }
  }
}

// ================= gemm256x: EXPERIMENTAL 8-phase counted-vmcnt =================
// 256x256 tile, BK=64, 512 thr, 2-buf LDS 128KB. 4 phases/K-tile, one C-quadrant each.
// Stage plan: P0->B0(t+1), P1->A1(t+1) [other buf]; P2->A0(t+2), P3->B1(t+2) [own buf].
// Single vmcnt(4) per K-tile before P3's end barrier. No sched_barrier.
template<int MODE>
__global__ __launch_bounds__(512, 1)
void gemm256x(const u16* __restrict__ A, const u16* __restrict__ B,
              void* __restrict__ C, const float* __restrict__ bias,
              int M, int N, int K, int lda)
{
  __shared__ alignas(16) char smem[132096];   // 2 x 64KB + 1KB dummy @131072

  int nwg = gridDim.x;
  int bx = blockIdx.x;
  if ((nwg & 7) == 0) bx = (bx & 7) * (nwg >> 3) + (bx >> 3);
  int GN = N >> 8;
  int bm = bx / GN, bn = bx - bm * GN;
  int m0 = bm << 8, n0 = bn << 8;

  int tid = threadIdx.x;
  int lane = tid & 63, wid = tid >> 6;
  int wm = wid >> 2, wn = wid & 3;   // wave out: rows [wm*128,+128), cols [wn*64,+64)

  int l3 = lane >> 3, l7 = lane & 7;
  int scol = ((l7 ^ l3) << 4);
  size_t ldab = (size_t)lda * 2;
  size_t ldbb = (size_t)K * 2;
  size_t plA = (size_t)l3 * ldab + scol;
  size_t plB = (size_t)l3 * ldbb + scol;
  int brow0w = ((wid & 3) << 3) + ((wid >> 2) << 6);

  int rowA0 = (wm * 128 + (lane & 15)) * 128;
  int rowB0 = (wn * 64 + (lane & 15)) * 128;
  int col0 = (((lane >> 4) << 4)) ^ (l7 << 4);
  int col1 = (((lane >> 4) << 4) + 64) ^ (l7 << 4);

  const int KT = K >> 6;

  auto stageA = [&](int tt, int m, int buf) {
    char* dst = smem + buf * 65536 + (m * 64 + wid * 8) * 128;
    const char* src = (const char*)A + (size_t)(m0 + m * 64 + wid * 8) * ldab + ((size_t)tt << 7);
    gload_lds16(src + plA, dst);
    gload_lds16(src + (size_t)128 * ldab + plA, dst + 16384);
  };
  auto stageB = [&](int tt, int n, int buf) {
    char* dst = smem + buf * 65536 + 32768 + (n * 32 + brow0w) * 128;
    const char* src = (const char*)B + (size_t)(n0 + n * 32 + brow0w) * ldbb + ((size_t)tt << 7);
    gload_lds16(src + plB, dst);
    gload_lds16(src + (size_t)128 * ldbb + plB, dst + 16384);
  };
  auto stageDummy = [&]() {
    gload_lds16((const char*)A + plA, smem + 131072);
    gload_lds16((const char*)A + plA, smem + 131072);
  };

  f32x4 acc[8][4] = {};

  // prologue: tile0 (8 loads), then A0(1), B1(1) (4 loads)
  stageA(0, 0, 0); stageA(0, 1, 0); stageB(0, 0, 0); stageB(0, 1, 0);
  stageA(1, 0, 1); stageB(1, 1, 1);
  asm volatile("s_waitcnt vmcnt(4)" ::: "memory");
  __builtin_amdgcn_s_barrier();

#define PHASE(MQ, NQ, STMT, TAILVM) do {                                      \
    char* bA = smem + cu * 65536;                                             \
    char* bB = bA + 32768;                                                    \
    bf16x8 avv[4][2], bvv[2][2];                                              \
    _Pragma("unroll")                                                         \
    for (int i = 0; i < 4; ++i) {                                             \
      avv[i][0] = *(const bf16x8*)(bA + rowA0 + ((MQ)*4 + i) * 2048 + col0);  \
      avv[i][1] = *(const bf16x8*)(bA + rowA0 + ((MQ)*4 + i) * 2048 + col1);  \
    }                                                                         \
    _Pragma("unroll")                                                         \
    for (int j = 0; j < 2; ++j) {                                             \
      bvv[j][0] = *(const bf16x8*)(bB + rowB0 + ((NQ)*2 + j) * 2048 + col0);  \
      bvv[j][1] = *(const bf16x8*)(bB + rowB0 + ((NQ)*2 + j) * 2048 + col1);  \
    }                                                                         \
    STMT;                                                                     \
    asm volatile("s_waitcnt lgkmcnt(8)" ::: "memory");                        \
    __builtin_amdgcn_s_barrier();                                             \
    asm volatile("s_waitcnt lgkmcnt(0)" ::: "memory");                        \
    __builtin_amdgcn_s_setprio(1);                                            \
    _Pragma("unroll")                                                         \
    for (int i = 0; i < 4; ++i)                                               \
      _Pragma("unroll")                                                       \
      for (int j = 0; j < 2; ++j) {                                           \
        acc[(MQ)*4 + i][(NQ)*2 + j] =                                         \
          __builtin_amdgcn_mfma_f32_16x16x32_bf16(avv[i][0], bvv[j][0],       \
                                                  acc[(MQ)*4 + i][(NQ)*2 + j], 0, 0, 0); \
        acc[(MQ)*4 + i][(NQ)*2 + j] =                                         \
          __builtin_amdgcn_mfma_f32_16x16x32_bf16(avv[i][1], bvv[j][1],       \
                                                  acc[(MQ)*4 + i][(NQ)*2 + j], 0, 0, 0); \
      }                                                                       \
    __builtin_amdgcn_s_setprio(0);                                            \
    TAILVM;                                                                   \
    __builtin_amdgcn_s_barrier();                                             \
  } while (0)

  for (int t = 0; t < KT; ++t) {
    int cu = t & 1;
    PHASE(0, 0, { if (t + 1 < KT) stageB(t + 1, 0, cu ^ 1); else stageDummy(); }, {});
    PHASE(0, 1, { if (t + 1 < KT) stageA(t + 1, 1, cu ^ 1); else stageDummy(); }, {});
    PHASE(1, 1, { if (t + 2 < KT) stageA(t + 2, 0, cu);     else stageDummy(); }, {});
    PHASE(1, 0, { if (t + 2 < KT) stageB(t + 2, 1, cu);     else stageDummy(); },
          { asm volatile("s_waitcnt vmcnt(4)" ::: "memory"); });
  }
#undef PHASE

  asm volatile("s_waitcnt vmcnt(0)" ::: "memory");

  // epilogue: frag row=(lane>>4)*4+r, col=lane&15
#pragma unroll
  for (int i = 0; i < 8; ++i) {
    int rb = m0 + wm * 128 + i * 16 + ((lane >> 4) << 2);
#pragma unroll
    for (int j = 0; j < 4; ++j) {
      int n = n0 + wn * 64 + j * 16 + (lane & 15);
      float bs = bias ? bias[n] : 0.f;
#pragma unroll
      for (int r = 0; r < 4; ++r) {
        int t = rb + r;
        float v = acc[i][j][r] + bs;
        if (MODE == 0)      ((u16*)C)[(size_t)t * N + n] = f2bf(v);
        else                ((float*)C)[(size_t)t * N + n] = v;
      }
    }
  }
}

// ---------------- softmax-weighted column sum ----------------
__global__ void summ_partial(const u16* __restrict__ logits, const u16* __restrict__ vals,
                             float* __restrict__ pm, float* __restrict__ pz,
                             float* __restrict__ pn, int remap)
{
  int tid = threadIdx.x;
  int sc = blockIdx.x, ec = blockIdx.y, b = blockIdx.z;
  int e = ec * 256 + tid;
  float m = -1e30f, z = 0.f, num = 0.f;
  int t0 = b * 4096 + sc * 128;
  for (int si = 0; si < 128; ++si) {
    int t = t0 + si;
    float l = bf2f(logits[(size_t)t * 1024 + e]);
    size_t vrow = remap ? ((size_t)t + 2 * b + 1) : (size_t)t;
    float v = bf2f(vals[vrow * 1024 + e]);
    float mn = fmaxf(m, l);
    float cc = __expf(m - mn);
    float p = __expf(l - mn);
    z = z * cc + p;
    num = num * cc + v * p;
    m = mn;
  }
  int pidx = (((b * 4 + ec) * 32) + sc) * 256 + tid;
  pm[pidx] = m; pz[pidx] = z; pn[pidx] = num;
}

__global__ void summ_combine(const float* __restrict__ pm, const float* __restrict__ pz,
                             const float* __restrict__ pn, float* __restrict__ summ)
{
  int idx = blockIdx.x * 256 + threadIdx.x;  // 0..4095 : b*1024+e
  int b = idx >> 10, e = idx & 1023;
  int ec = e >> 8, tt = e & 255;
  const int base = ((b * 4 + ec) * 32) * 256 + tt;
  float M = -1e30f;
  for (int sc = 0; sc < 32; ++sc) M = fmaxf(M, pm[base + sc * 256]);
  float Z = 0.f, Nm = 0.f;
  for (int sc = 0; sc < 32; ++sc) {
    float w = __expf(pm[base + sc * 256] - M);
    Z += pz[base + sc * 256] * w;
    Nm += pn[base + sc * 256] * w;
  }
  summ[idx] = Nm / Z;
}

// ---------------- elementwise ----------------
__global__ void pk(const u16* __restrict__ O, const float* __restrict__ s1,
                   u16* __restrict__ P, u16* __restrict__ GP)
{
  size_t idx = (size_t)blockIdx.x * 256 + threadIdx.x;
  size_t base = idx * 8;
  int t = (int)(base >> 10);
  int b = t >> 12;
  int e = (int)(base & 1023);
  const float* sp = s1 + b * 1024 + e;
  u16x8 ov = *(const u16x8*)(O + base);
  u16x8 pv, gv;
#pragma unroll
  for (int j = 0; j < 8; ++j) {
    float p = bf2f(ov[j]) * sp[j];
    pv[j] = f2bf(p);
    gv[j] = f2bf(geluf(p));
  }
  *(u16x8*)(P + base) = pv;
  *(u16x8*)(GP + base) = gv;
}

__global__ void lk(const u16* __restrict__ G, const float* __restrict__ s2,
                   u16* __restrict__ L)
{
  size_t idx = (size_t)blockIdx.x * 256 + threadIdx.x;
  size_t base = idx * 8;
  int t = (int)(base >> 10);
  int b = t >> 12;
  int e = (int)(base & 1023);
  const float* sp = s2 + b * 1024 + e;
  u16x8 gvv = *(const u16x8*)(G + base);
  u16x8 lv;
#pragma unroll
  for (int j = 0; j < 8; ++j) {
    lv[j] = f2bf(siluf(bf2f(gvv[j])) * sp[j]);
  }
  *(u16x8*)(L + base) = lv;
}

// ---------------- launch ----------------
extern "C" void kernel_launch(void* const* d_in, const int* in_sizes, int n_in,
                              void* d_out, int out_size, void* d_ws, size_t ws_size,
                              hipStream_t stream)
{
  const float* x     = (const float*)d_in[0];
  const float* Wq    = (const float*)d_in[1];
  const float* Wqb   = (const float*)d_in[2];
  const float* Wo    = (const float*)d_in[3];
  const float* Wob   = (const float*)d_in[4];
  const float* Wg    = (const float*)d_in[5];
  const float* Wgb   = (const float*)d_in[6];
  const float* wa    = (const float*)d_in[7];
  const float* wb    = (const float*)d_in[8];
  const float* Wout  = (const float*)d_in[9];
  const float* Woutb = (const float*)d_in[10];
  const float* convw = (const float*)d_in[11];
  const float* convb = (const float*)d_in[12];

  char* ws = (char*)d_ws;
  size_t off = 0;
  auto alloc = [&](size_t bytes) -> char* {
    char* p = ws + off;
    off += (bytes + 255) & ~(size_t)255;
    return p;
  };

  u16* QPAD = (u16*)alloc((size_t)4 * SPAD * 1024 * 2);   // Qpad -> later P (plain layout)
  u16* OB   = (u16*)alloc((size_t)NT * 1024 * 2);         // O    -> later L
  u16* GB   = (u16*)alloc((size_t)NT * 1024 * 2);         // G
  u16* XB   = (u16*)alloc((size_t)NT * 1024 * 2);         // x_bf16 -> GA -> GP
  u16* SS   = (u16*)alloc((size_t)NT * 1024 * 2);         // logits A -> logits B
  u16* WALL = (u16*)alloc((size_t)6 * 1024 * 1024 * 2);   // [Wq,Wo,Wg,wa*s,wb*s,Wout]
  u16* WCB_ = (u16*)alloc((size_t)1024 * 3072 * 2);
  float* PM = (float*)alloc((size_t)4 * 4 * 32 * 256 * 4);
  float* PZ = (float*)alloc((size_t)4 * 4 * 32 * 256 * 4);
  float* PN = (float*)alloc((size_t)4 * 4 * 32 * 256 * 4);
  float* S1 = (float*)alloc((size_t)4096 * 4);
  float* S2 = (float*)alloc((size_t)4096 * 4);

  if (off > ws_size) return;

  u16* WQOG   = WALL;
  u16* WAB_   = WALL + (size_t)3 * 1048576;
  u16* WBB_   = WALL + (size_t)4 * 1048576;
  u16* WOUTB_ = WALL + (size_t)5 * 1048576;

  u16* PB = QPAD;  // P in plain [NT,1024] layout (Q dead by then)
  u16* GA = XB;
  u16* GP = XB;
  u16* LB = OB;

  const float scale = 0.03125f;  // 1/sqrt(1024)

  // 1. converts
  cvtk<<<16384, 256, 0, stream>>>(x, XB, 4194304, 1.0f);
  cvtw6<<<6144, 256, 0, stream>>>(Wq, Wo, Wg, wa, wb, Wout, WALL, scale);
  cvt_convw<<<4096, 256, 0, stream>>>(convw, WCB_);
  zero_halo<<<32, 256, 0, stream>>>(QPAD);

  // 2. fused Q/O/G GEMM (proven 128^2 structure): N=3072, routed epilogue
  gemm128<4><<<128 * 24, 256, 0, stream>>>(XB, WQOG, QPAD, Wqb, OB, GB, Wob, Wgb,
                                           NT, 3072, 1024, 1024);

  // 3. conv as GEMM (A = Qpad, K = 3072), epilogue gelu(silu(.)) -> GA
  gemm128<2><<<128 * 8, 256, 0, stream>>>(QPAD, WCB_, GA, convb, nullptr, nullptr, nullptr, nullptr,
                                          NT, 1024, 3072, 1024);

  // 4. logits A = GA @ (wa*scale)^T -> SS   [EXPERIMENT: 8-phase 256^2]
  gemm256x<0><<<64 * 4, 512, 0, stream>>>(GA, WAB_, SS, nullptr, NT, 1024, 1024, 1024);

  // 5. summ1 = softmax-weighted sum of Q
  {
    dim3 g(32, 4, 4);
    summ_partial<<<g, 256, 0, stream>>>(SS, QPAD, PM, PZ, PN, 1);
    summ_combine<<<16, 256, 0, stream>>>(PM, PZ, PN, S1);
  }

  // 6. P = O * summ1 ; GP = gelu(P)
  pk<<<8192, 256, 0, stream>>>(OB, S1, PB, GP);

  // 7. logits B = GP @ (wb*scale)^T -> SS   [CONTROL: same shape as step 4]
  gemm128<0><<<128 * 8, 256, 0, stream>>>(GP, WBB_, SS, nullptr, nullptr, nullptr, nullptr, nullptr,
                                          NT, 1024, 1024, 1024);

  // 8. summ2 = softmax-weighted sum of P
  {
    dim3 g(32, 4, 4);
    summ_partial<<<g, 256, 0, stream>>>(SS, PB, PM, PZ, PN, 0);
    summ_combine<<<16, 256, 0, stream>>>(PM, PZ, PN, S2);
  }

  // 9. L = silu(G) * summ2
  lk<<<8192, 256, 0, stream>>>(GB, S2, LB);

  // 10. out = L @ Wout^T + b  (fp32)
  gemm128<3><<<128 * 8, 256, 0, stream>>>(LB, WOUTB_, d_out, Woutb, nullptr, nullptr, nullptr, nullptr,
                                          NT, 1024, 1024, 1024);
}

// Round 5
// 467.960 us; speedup vs baseline: 1.1723x; 1.0409x over previous
//
#include <hip/hip_runtime.h>
#include <stdint.h>

#define DEV __device__ __forceinline__

typedef unsigned short u16;
typedef unsigned int u32;

typedef __bf16 bf16x8 __attribute__((ext_vector_type(8)));
typedef float f32x4 __attribute__((ext_vector_type(4)));
typedef u16 u16x8 __attribute__((ext_vector_type(8)));
typedef u16 u16x4 __attribute__((ext_vector_type(4)));

static_assert(sizeof(bf16x8) == 16, "bf16x8 must be 16B");

#define NT 16384      // B*S = 4*4096
#define SPAD 4098     // S + 2 halo rows per batch

DEV u16 f2bf(float f) {
  u32 u = __float_as_uint(f);
  u32 r = u + 0x7FFFu + ((u >> 16) & 1u);
  return (u16)(r >> 16);
}
DEV float bf2f(u16 h) { return __uint_as_float(((u32)h) << 16); }
DEV float siluf(float x) { return x / (1.f + __expf(-x)); }
DEV float geluf(float x) { return 0.5f * x * (1.f + erff(x * 0.70710678118654752f)); }

DEV void gload_lds16(const void* g, void* l) {
  __builtin_amdgcn_global_load_lds((const __attribute__((address_space(1))) void*)g,
                                   (__attribute__((address_space(3))) void*)l,
                                   16, 0, 0);
}

// ---------------- converts ----------------
__global__ void cvtk(const float* __restrict__ in, u16* __restrict__ out, int n4, float scale) {
  int i = blockIdx.x * 256 + threadIdx.x;
  if (i >= n4) return;
  const float4 v = *(const float4*)(in + (size_t)i * 4);
  u16x4 o;
  o[0] = f2bf(v.x * scale); o[1] = f2bf(v.y * scale);
  o[2] = f2bf(v.z * scale); o[3] = f2bf(v.w * scale);
  *(u16x4*)(out + (size_t)i * 4) = o;
}

// 6 d*d weight matrices -> one contiguous bf16 buffer [Wq,Wo,Wg,wa*s,wb*s,Wout]
__global__ void cvtw6(const float* __restrict__ w0, const float* __restrict__ w1,
                      const float* __restrict__ w2, const float* __restrict__ w3,
                      const float* __restrict__ w4, const float* __restrict__ w5,
                      u16* __restrict__ dst, float s) {
  int idx = blockIdx.x * 256 + threadIdx.x;      // 6 * 262144 four-elem groups
  int mat = idx >> 18, within = idx & 262143;
  const float* src; float sc = 1.0f;
  if (mat == 0) src = w0;
  else if (mat == 1) src = w1;
  else if (mat == 2) src = w2;
  else if (mat == 3) { src = w3; sc = s; }
  else if (mat == 4) { src = w4; sc = s; }
  else src = w5;
  const float4 v = *(const float4*)(src + (size_t)within * 4);
  u16x4 o;
  o[0] = f2bf(v.x * sc); o[1] = f2bf(v.y * sc);
  o[2] = f2bf(v.z * sc); o[3] = f2bf(v.w * sc);
  *(u16x4*)(dst + (size_t)idx * 4) = o;
}

// conv_w [o][d][3] -> Wc [o][tap*1024 + d]
__global__ void cvt_convw(const float* __restrict__ cw, u16* __restrict__ Wc) {
  int i = blockIdx.x * 256 + threadIdx.x;   // 1M threads: o*1024+d
  int o = i >> 10, d = i & 1023;
  const float* src = cw + ((size_t)o * 1024 + d) * 3;
  u16* dst = Wc + (size_t)o * 3072 + d;
  dst[0]    = f2bf(src[0]);
  dst[1024] = f2bf(src[1]);
  dst[2048] = f2bf(src[2]);
}

// zero the 2 halo rows of each batch in Qpad
__global__ void zero_halo(u16* __restrict__ Qpad) {
  int i = blockIdx.x * 256 + threadIdx.x;   // 8192 threads
  int r = i >> 10, c = i & 1023;
  int b = r >> 1, side = r & 1;
  size_t row = (size_t)b * SPAD + (side ? (SPAD - 1) : 0);
  Qpad[row * 1024 + c] = 0;
}

// ================= gemm128: PROVEN structure (~888 TF) =================
// 128x128 tile, BK=64, 256 thr, single-buffer LDS + syncthreads drain.
// MODE 0: bf16 out (+bias). MODE 2: conv A-addressing, epilogue gelu(silu(v+b)).
// MODE 3: f32 out. MODE 4: QOG fused, seg = n>>10 (block-uniform), Q->Qpad remap.
template<int MODE>
__global__ __launch_bounds__(256, 2)
void gemm128(const u16* __restrict__ A, const u16* __restrict__ B,
             void* __restrict__ C, const float* __restrict__ bias,
             void* __restrict__ C2, void* __restrict__ C3,
             const float* __restrict__ bias2, const float* __restrict__ bias3,
             int M, int N, int K, int lda)
{
  __shared__ alignas(16) char smem[32768];
  char* sA = smem;
  char* sB = smem + 16384;

  int nwg = gridDim.x;
  int bx = blockIdx.x;
  if ((nwg & 7) == 0) bx = (bx & 7) * (nwg >> 3) + (bx >> 3);  // XCD swizzle (bijective)
  int GN = N >> 7;
  int bm = bx / GN, bn = bx - bm * GN;
  int m0 = bm << 7, n0 = bn << 7;

  int tid = threadIdx.x;
  int lane = tid & 63, wid = tid >> 6;
  int wm = wid >> 1, wn = wid & 1;

  f32x4 acc[4][4] = {};

  int strow = tid >> 3;            // 0..31
  int stcolb = (tid & 7) << 4;     // byte col 0..112
  size_t ldab = (size_t)lda * 2;
  size_t ldbb = (size_t)K * 2;
  int bofm = m0 >> 12;             // batch of this m-tile (tiles never straddle batches)

  const int KT = K >> 6;
  for (int kt = 0; kt < KT; ++kt) {
    int k0 = kt << 6;
    const char* Ab;
    if (MODE == 2) {
      int tap = k0 >> 10;
      Ab = (const char*)(A + ((size_t)(m0 + 2 * bofm + tap) * (size_t)lda + (k0 & 1023)));
    } else {
      Ab = (const char*)(A + ((size_t)m0 * (size_t)lda + k0));
    }
    const char* Bb = (const char*)(B + ((size_t)n0 * (size_t)K + k0));
#pragma unroll
    for (int j = 0; j < 4; ++j) {
      int row = j * 32 + strow;
      int sw = (row & 7) << 4;     // XOR swizzle on 16B granules (involution)
      gload_lds16(Ab + (size_t)row * ldab + (size_t)(stcolb ^ sw), sA + j * 4096 + wid * 1024);
      gload_lds16(Bb + (size_t)row * ldbb + (size_t)(stcolb ^ sw), sB + j * 4096 + wid * 1024);
    }
    __syncthreads();
#pragma unroll
    for (int kk = 0; kk < 2; ++kk) {
      bf16x8 av[4], bv[4];
      int cb = ((lane >> 4) << 4) + (kk << 6);
#pragma unroll
      for (int i = 0; i < 4; ++i) {
        int r = (wm << 6) + (i << 4) + (lane & 15);
        av[i] = *(const bf16x8*)(sA + r * 128 + (cb ^ ((r & 7) << 4)));
      }
#pragma unroll
      for (int j = 0; j < 4; ++j) {
        int r = (wn << 6) + (j << 4) + (lane & 15);
        bv[j] = *(const bf16x8*)(sB + r * 128 + (cb ^ ((r & 7) << 4)));
      }
#pragma unroll
      for (int i = 0; i < 4; ++i)
#pragma unroll
        for (int j = 0; j < 4; ++j)
          acc[i][j] = __builtin_amdgcn_mfma_f32_16x16x32_bf16(av[i], bv[j], acc[i][j], 0, 0, 0);
    }
    __syncthreads();
  }

  // epilogue: frag row=(lane>>4)*4+r, col=lane&15
#pragma unroll
  for (int i = 0; i < 4; ++i) {
    int rb = m0 + (wm << 6) + (i << 4) + ((lane >> 4) << 2);
#pragma unroll
    for (int j = 0; j < 4; ++j) {
      int n = n0 + (wn << 6) + (j << 4) + (lane & 15);
      if (MODE == 4) {
        int seg = n >> 10, nn = n & 1023;    // seg is block-uniform (128 | 1024)
        const float* bsel = (seg == 0) ? bias : ((seg == 1) ? bias2 : bias3);
        float bs = bsel ? bsel[nn] : 0.f;
#pragma unroll
        for (int r = 0; r < 4; ++r) {
          int t = rb + r;
          u16 h = f2bf(acc[i][j][r] + bs);
          if (seg == 0) {
            size_t row = (size_t)t + 2 * (t >> 12) + 1;   // Q -> Qpad remap
            ((u16*)C)[row * 1024 + nn] = h;
          } else if (seg == 1) {
            ((u16*)C2)[(size_t)t * 1024 + nn] = h;
          } else {
            ((u16*)C3)[(size_t)t * 1024 + nn] = h;
          }
        }
      } else {
        float bs = bias ? bias[n] : 0.f;
#pragma unroll
        for (int r = 0; r < 4; ++r) {
          int t = rb + r;
          float v = acc[i][j][r] + bs;
          if (MODE == 0)      ((u16*)C)[(size_t)t * N + n] = f2bf(v);
          else if (MODE == 2) ((u16*)C)[(size_t)t * N + n] = f2bf(geluf(siluf(v)));
          else                ((float*)C)[(size_t)t * N + n] = v;
        }
      }
    }
  }
}

// ---------------- softmax-weighted column sum ----------------
// per (b,e): m=max_s l, Z=sum exp(l-m), num=sum v*exp(l-m)
__global__ void summ_partial(const u16* __restrict__ logits, const u16* __restrict__ vals,
                             float* __restrict__ pm, float* __restrict__ pz,
                             float* __restrict__ pn, int remap)
{
  int tid = threadIdx.x;
  int sc = blockIdx.x, ec = blockIdx.y, b = blockIdx.z;
  int e = ec * 256 + tid;
  float m = -1e30f, z = 0.f, num = 0.f;
  int t0 = b * 4096 + sc * 128;
  for (int si = 0; si < 128; ++si) {
    int t = t0 + si;
    float l = bf2f(logits[(size_t)t * 1024 + e]);
    size_t vrow = remap ? ((size_t)t + 2 * b + 1) : (size_t)t;
    float v = bf2f(vals[vrow * 1024 + e]);
    float mn = fmaxf(m, l);
    float cc = __expf(m - mn);
    float p = __expf(l - mn);
    z = z * cc + p;
    num = num * cc + v * p;
    m = mn;
  }
  int pidx = (((b * 4 + ec) * 32) + sc) * 256 + tid;
  pm[pidx] = m; pz[pidx] = z; pn[pidx] = num;
}

// summ = (num/Z) * (mul ? mul : 1)
__global__ void summ_combine(const float* __restrict__ pm, const float* __restrict__ pz,
                             const float* __restrict__ pn, const float* __restrict__ mul,
                             float* __restrict__ summ)
{
  int idx = blockIdx.x * 256 + threadIdx.x;  // 0..4095 : b*1024+e
  int b = idx >> 10, e = idx & 1023;
  int ec = e >> 8, tt = e & 255;
  const int base = ((b * 4 + ec) * 32) * 256 + tt;
  float M = -1e30f;
  for (int sc = 0; sc < 32; ++sc) M = fmaxf(M, pm[base + sc * 256]);
  float Z = 0.f, Nm = 0.f;
  for (int sc = 0; sc < 32; ++sc) {
    float w = __expf(pm[base + sc * 256] - M);
    Z += pz[base + sc * 256] * w;
    Nm += pn[base + sc * 256] * w;
  }
  float r = Nm / Z;
  summ[idx] = mul ? r * mul[idx] : r;
}

// ---------------- elementwise ----------------
// GP = gelu(O * s1[b,:])   (P itself never materialized)
__global__ void pk(const u16* __restrict__ O, const float* __restrict__ s1,
                   u16* __restrict__ GP)
{
  size_t idx = (size_t)blockIdx.x * 256 + threadIdx.x;
  size_t base = idx * 8;
  int t = (int)(base >> 10);
  int b = t >> 12;
  int e = (int)(base & 1023);
  const float* sp = s1 + b * 1024 + e;
  u16x8 ov = *(const u16x8*)(O + base);
  u16x8 gv;
#pragma unroll
  for (int j = 0; j < 8; ++j) {
    gv[j] = f2bf(geluf(bf2f(ov[j]) * sp[j]));
  }
  *(u16x8*)(GP + base) = gv;
}

// L = silu(G) * summ2[b,:]
__global__ void lk(const u16* __restrict__ G, const float* __restrict__ s2,
                   u16* __restrict__ L)
{
  size_t idx = (size_t)blockIdx.x * 256 + threadIdx.x;
  size_t base = idx * 8;
  int t = (int)(base >> 10);
  int b = t >> 12;
  int e = (int)(base & 1023);
  const float* sp = s2 + b * 1024 + e;
  u16x8 gvv = *(const u16x8*)(G + base);
  u16x8 lv;
#pragma unroll
  for (int j = 0; j < 8; ++j) {
    lv[j] = f2bf(siluf(bf2f(gvv[j])) * sp[j]);
  }
  *(u16x8*)(L + base) = lv;
}

// ---------------- launch ----------------
extern "C" void kernel_launch(void* const* d_in, const int* in_sizes, int n_in,
                              void* d_out, int out_size, void* d_ws, size_t ws_size,
                              hipStream_t stream)
{
  const float* x     = (const float*)d_in[0];
  const float* Wq    = (const float*)d_in[1];
  const float* Wqb   = (const float*)d_in[2];
  const float* Wo    = (const float*)d_in[3];
  const float* Wob   = (const float*)d_in[4];
  const float* Wg    = (const float*)d_in[5];
  const float* Wgb   = (const float*)d_in[6];
  const float* wa    = (const float*)d_in[7];
  const float* wb    = (const float*)d_in[8];
  const float* Wout  = (const float*)d_in[9];
  const float* Woutb = (const float*)d_in[10];
  const float* convw = (const float*)d_in[11];
  const float* convb = (const float*)d_in[12];

  char* ws = (char*)d_ws;
  size_t off = 0;
  auto alloc = [&](size_t bytes) -> char* {
    char* p = ws + off;
    off += (bytes + 255) & ~(size_t)255;
    return p;
  };

  u16* QPAD = (u16*)alloc((size_t)4 * SPAD * 1024 * 2);   // Qpad (halo layout)
  u16* OB   = (u16*)alloc((size_t)NT * 1024 * 2);         // O -> later L
  u16* GB   = (u16*)alloc((size_t)NT * 1024 * 2);         // G
  u16* XB   = (u16*)alloc((size_t)NT * 1024 * 2);         // x_bf16 -> GA -> GP
  u16* SS   = (u16*)alloc((size_t)NT * 1024 * 2);         // logits A -> logits B
  u16* WALL = (u16*)alloc((size_t)6 * 1024 * 1024 * 2);   // [Wq,Wo,Wg,wa*s,wb*s,Wout]
  u16* WCB_ = (u16*)alloc((size_t)1024 * 3072 * 2);
  float* PM = (float*)alloc((size_t)4 * 4 * 32 * 256 * 4);
  float* PZ = (float*)alloc((size_t)4 * 4 * 32 * 256 * 4);
  float* PN = (float*)alloc((size_t)4 * 4 * 32 * 256 * 4);
  float* S1 = (float*)alloc((size_t)4096 * 4);
  float* S2 = (float*)alloc((size_t)4096 * 4);

  if (off > ws_size) return;

  u16* WQOG   = WALL;
  u16* WAB_   = WALL + (size_t)3 * 1048576;
  u16* WBB_   = WALL + (size_t)4 * 1048576;
  u16* WOUTB_ = WALL + (size_t)5 * 1048576;

  u16* GA = XB;
  u16* GP = XB;
  u16* LB = OB;

  const float scale = 0.03125f;  // 1/sqrt(1024)

  // 1. converts
  cvtk<<<16384, 256, 0, stream>>>(x, XB, 4194304, 1.0f);
  cvtw6<<<6144, 256, 0, stream>>>(Wq, Wo, Wg, wa, wb, Wout, WALL, scale);
  cvt_convw<<<4096, 256, 0, stream>>>(convw, WCB_);
  zero_halo<<<32, 256, 0, stream>>>(QPAD);

  // 2. fused Q/O/G GEMM: N=3072, routed epilogue (Q remapped into QPAD)
  gemm128<4><<<128 * 24, 256, 0, stream>>>(XB, WQOG, QPAD, Wqb, OB, GB, Wob, Wgb,
                                           NT, 3072, 1024, 1024);

  // 3. conv as GEMM (A = Qpad, K = 3072), epilogue gelu(silu(.)) -> GA
  gemm128<2><<<128 * 8, 256, 0, stream>>>(QPAD, WCB_, GA, convb, nullptr, nullptr, nullptr, nullptr,
                                          NT, 1024, 3072, 1024);

  // 4. logits A = GA @ (wa*scale)^T -> SS
  gemm128<0><<<128 * 8, 256, 0, stream>>>(GA, WAB_, SS, nullptr, nullptr, nullptr, nullptr, nullptr,
                                          NT, 1024, 1024, 1024);

  // 5. summ1 = softmax-weighted sum of Q (vals read from Qpad w/ halo remap)
  {
    dim3 g(32, 4, 4);
    summ_partial<<<g, 256, 0, stream>>>(SS, QPAD, PM, PZ, PN, 1);
    summ_combine<<<16, 256, 0, stream>>>(PM, PZ, PN, nullptr, S1);
  }

  // 6. GP = gelu(O * summ1)  (P never materialized)
  pk<<<8192, 256, 0, stream>>>(OB, S1, GP);

  // 7. logits B = GP @ (wb*scale)^T -> SS
  gemm128<0><<<128 * 8, 256, 0, stream>>>(GP, WBB_, SS, nullptr, nullptr, nullptr, nullptr, nullptr,
                                          NT, 1024, 1024, 1024);

  // 8. summ2 = s1 * softmax-weighted sum of O  (== softmax-weighted sum of P)
  {
    dim3 g(32, 4, 4);
    summ_partial<<<g, 256, 0, stream>>>(SS, OB, PM, PZ, PN, 0);
    summ_combine<<<16, 256, 0, stream>>>(PM, PZ, PN, S1, S2);
  }

  // 9. L = silu(G) * summ2
  lk<<<8192, 256, 0, stream>>>(GB, S2, LB);

  // 10. out = L @ Wout^T + b  (fp32)
  gemm128<3><<<128 * 8, 256, 0, stream>>>(LB, WOUTB_, d_out, Woutb, nullptr, nullptr, nullptr, nullptr,
                                          NT, 1024, 1024, 1024);
}

// Round 6
// 449.202 us; speedup vs baseline: 1.2213x; 1.0418x over previous
//
#include <hip/hip_runtime.h>
#include <stdint.h>

#define DEV __device__ __forceinline__

typedef unsigned short u16;
typedef unsigned int u32;
typedef unsigned char u8;

typedef __bf16 bf16x8 __attribute__((ext_vector_type(8)));
typedef float f32x4 __attribute__((ext_vector_type(4)));
typedef u16 u16x8 __attribute__((ext_vector_type(8)));
typedef u16 u16x4 __attribute__((ext_vector_type(4)));
typedef u8 u8x8 __attribute__((ext_vector_type(8)));
typedef int i32x4 __attribute__((ext_vector_type(4)));
typedef int i32x8 __attribute__((ext_vector_type(8)));

static_assert(sizeof(bf16x8) == 16, "bf16x8 must be 16B");

#define NT 16384      // B*S = 4*4096
#define SPAD 4098     // S + 2 halo rows per batch

DEV u16 f2bf(float f) {
  u32 u = __float_as_uint(f);
  u32 r = u + 0x7FFFu + ((u >> 16) & 1u);
  return (u16)(r >> 16);
}
DEV float bf2f(u16 h) { return __uint_as_float(((u32)h) << 16); }
DEV float siluf(float x) { return x / (1.f + __expf(-x)); }
DEV float geluf(float x) { return 0.5f * x * (1.f + erff(x * 0.70710678118654752f)); }

// float -> OCP e4m3fn (RNE for normals, half-up for subnormals, clamp to 448)
DEV u8 f2fp8(float f) {
  u32 u = __float_as_uint(f);
  u32 s = (u >> 24) & 0x80u;
  u32 a = u & 0x7FFFFFFFu;
  if (a >= 0x43E00000u) return (u8)(s | 0x7E);      // >= 448 -> max finite
  if (a < 0x3C800000u) {                             // < 2^-6 -> subnormal (step 2^-9)
    float q = __uint_as_float(a) * 512.f;
    u32 m = (u32)(q + 0.5f);                         // 0..8 (8 carries to min normal)
    return (u8)(s | m);
  }
  u32 r = a + 0xFFFFFu + ((a >> 20) & 1u);           // RNE to 3 mantissa bits
  if (r >= 0x43E00000u) return (u8)(s | 0x7E);
  u32 e = (r >> 23) - 120u;                          // biased-7 exponent, 1..15
  u32 m = (r >> 20) & 7u;
  return (u8)(s | (e << 3) | m);
}

DEV void gload_lds16(const void* g, void* l) {
  __builtin_amdgcn_global_load_lds((const __attribute__((address_space(1))) void*)g,
                                   (__attribute__((address_space(3))) void*)l,
                                   16, 0, 0);
}

DEV f32x4 mfma_mx(i32x8 a, i32x8 b, f32x4 c) {
  // fp8(e4m3) x fp8, unit scales (E8M0 127 = 2^0) -> scale-block mapping irrelevant
  return __builtin_amdgcn_mfma_scale_f32_16x16x128_f8f6f4(
      a, b, c, 0, 0, 0, 0x7F7F7F7Fu, 0, 0x7F7F7F7Fu);
}

// ---------------- converts ----------------
__global__ void cvtk(const float* __restrict__ in, u16* __restrict__ out, int n4, float scale) {
  int i = blockIdx.x * 256 + threadIdx.x;
  if (i >= n4) return;
  const float4 v = *(const float4*)(in + (size_t)i * 4);
  u16x4 o;
  o[0] = f2bf(v.x * scale); o[1] = f2bf(v.y * scale);
  o[2] = f2bf(v.z * scale); o[3] = f2bf(v.w * scale);
  *(u16x4*)(out + (size_t)i * 4) = o;
}

// 4 d*d weight matrices -> one contiguous bf16 buffer [Wq,Wo,Wg,Wout]
__global__ void cvtw4(const float* __restrict__ w0, const float* __restrict__ w1,
                      const float* __restrict__ w2, const float* __restrict__ w3,
                      u16* __restrict__ dst) {
  int idx = blockIdx.x * 256 + threadIdx.x;      // 4 * 262144 four-elem groups
  int mat = idx >> 18, within = idx & 262143;
  const float* src = (mat == 0) ? w0 : (mat == 1) ? w1 : (mat == 2) ? w2 : w3;
  const float4 v = *(const float4*)(src + (size_t)within * 4);
  u16x4 o;
  o[0] = f2bf(v.x); o[1] = f2bf(v.y); o[2] = f2bf(v.z); o[3] = f2bf(v.w);
  *(u16x4*)(dst + (size_t)idx * 4) = o;
}

// wa, wb -> fp8 (UNscaled; 1/32 logit scale applied in GEMM epilogue)
__global__ void cvtw_f8(const float* __restrict__ wa, const float* __restrict__ wb,
                        u8* __restrict__ dst) {
  int idx = blockIdx.x * 256 + threadIdx.x;      // 2 * 262144
  const float* src = (idx >> 18) ? wb : wa;
  int within = idx & 262143;
  const float4 v = *(const float4*)(src + (size_t)within * 4);
  u32 o = (u32)f2fp8(v.x) | ((u32)f2fp8(v.y) << 8) |
          ((u32)f2fp8(v.z) << 16) | ((u32)f2fp8(v.w) << 24);
  *(u32*)(dst + (size_t)idx * 4) = o;
}

// conv_w [o][d][3] -> fp8 Wc [o][tap*1024 + d]
__global__ void cvt_convw8(const float* __restrict__ cw, u8* __restrict__ Wc) {
  int i = blockIdx.x * 256 + threadIdx.x;   // 1M threads: o*1024+d
  int o = i >> 10, d = i & 1023;
  const float* src = cw + ((size_t)o * 1024 + d) * 3;
  u8* dst = Wc + (size_t)o * 3072 + d;
  dst[0]    = f2fp8(src[0]);
  dst[1024] = f2fp8(src[1]);
  dst[2048] = f2fp8(src[2]);
}

// zero the 2 halo rows of each batch in fp8 Qpad
__global__ void zero_halo8(u8* __restrict__ Qpad8) {
  int i = blockIdx.x * 256 + threadIdx.x;   // 8192 threads
  int r = i >> 10, c = i & 1023;
  int b = r >> 1, side = r & 1;
  size_t row = (size_t)b * SPAD + (side ? (SPAD - 1) : 0);
  Qpad8[row * 1024 + c] = 0;
}

// ================= gemm128: PROVEN bf16 structure (~888 TF) =================
// MODE 0: bf16 out (+bias). MODE 3: f32 out.
// MODE 4: QOG fused, seg=n>>10: Q-> C(bf16 plain) + C4(fp8 halo); O->C2; G->C3.
template<int MODE>
__global__ __launch_bounds__(256, 2)
void gemm128(const u16* __restrict__ A, const u16* __restrict__ B,
             void* __restrict__ C, const float* __restrict__ bias,
             void* __restrict__ C2, void* __restrict__ C3, void* __restrict__ C4,
             const float* __restrict__ bias2, const float* __restrict__ bias3,
             int M, int N, int K, int lda)
{
  __shared__ alignas(16) char smem[32768];
  char* sA = smem;
  char* sB = smem + 16384;

  int nwg = gridDim.x;
  int bx = blockIdx.x;
  if ((nwg & 7) == 0) bx = (bx & 7) * (nwg >> 3) + (bx >> 3);  // XCD swizzle (bijective)
  int GN = N >> 7;
  int bm = bx / GN, bn = bx - bm * GN;
  int m0 = bm << 7, n0 = bn << 7;

  int tid = threadIdx.x;
  int lane = tid & 63, wid = tid >> 6;
  int wm = wid >> 1, wn = wid & 1;

  f32x4 acc[4][4] = {};

  int strow = tid >> 3;            // 0..31
  int stcolb = (tid & 7) << 4;     // byte col 0..112
  size_t ldab = (size_t)lda * 2;
  size_t ldbb = (size_t)K * 2;

  const int KT = K >> 6;
  for (int kt = 0; kt < KT; ++kt) {
    int k0 = kt << 6;
    const char* Ab = (const char*)(A + ((size_t)m0 * (size_t)lda + k0));
    const char* Bb = (const char*)(B + ((size_t)n0 * (size_t)K + k0));
#pragma unroll
    for (int j = 0; j < 4; ++j) {
      int row = j * 32 + strow;
      int sw = (row & 7) << 4;     // XOR swizzle on 16B granules (involution)
      gload_lds16(Ab + (size_t)row * ldab + (size_t)(stcolb ^ sw), sA + j * 4096 + wid * 1024);
      gload_lds16(Bb + (size_t)row * ldbb + (size_t)(stcolb ^ sw), sB + j * 4096 + wid * 1024);
    }
    __syncthreads();
#pragma unroll
    for (int kk = 0; kk < 2; ++kk) {
      bf16x8 av[4], bv[4];
      int cb = ((lane >> 4) << 4) + (kk << 6);
#pragma unroll
      for (int i = 0; i < 4; ++i) {
        int r = (wm << 6) + (i << 4) + (lane & 15);
        av[i] = *(const bf16x8*)(sA + r * 128 + (cb ^ ((r & 7) << 4)));
      }
#pragma unroll
      for (int j = 0; j < 4; ++j) {
        int r = (wn << 6) + (j << 4) + (lane & 15);
        bv[j] = *(const bf16x8*)(sB + r * 128 + (cb ^ ((r & 7) << 4)));
      }
#pragma unroll
      for (int i = 0; i < 4; ++i)
#pragma unroll
        for (int j = 0; j < 4; ++j)
          acc[i][j] = __builtin_amdgcn_mfma_f32_16x16x32_bf16(av[i], bv[j], acc[i][j], 0, 0, 0);
    }
    __syncthreads();
  }

  // epilogue: frag row=(lane>>4)*4+r, col=lane&15
#pragma unroll
  for (int i = 0; i < 4; ++i) {
    int rb = m0 + (wm << 6) + (i << 4) + ((lane >> 4) << 2);
#pragma unroll
    for (int j = 0; j < 4; ++j) {
      int n = n0 + (wn << 6) + (j << 4) + (lane & 15);
      if (MODE == 4) {
        int seg = n >> 10, nn = n & 1023;    // seg is block-uniform (128 | 1024)
        const float* bsel = (seg == 0) ? bias : ((seg == 1) ? bias2 : bias3);
        float bs = bsel ? bsel[nn] : 0.f;
#pragma unroll
        for (int r = 0; r < 4; ++r) {
          int t = rb + r;
          float v = acc[i][j][r] + bs;
          u16 h = f2bf(v);
          if (seg == 0) {
            ((u16*)C)[(size_t)t * 1024 + nn] = h;               // Q bf16 (summ values)
            size_t row = (size_t)t + 2 * (t >> 12) + 1;         // halo remap
            ((u8*)C4)[row * 1024 + nn] = f2fp8(v);              // Q fp8 (conv input)
          } else if (seg == 1) {
            ((u16*)C2)[(size_t)t * 1024 + nn] = h;
          } else {
            ((u16*)C3)[(size_t)t * 1024 + nn] = h;
          }
        }
      } else {
        float bs = bias ? bias[n] : 0.f;
#pragma unroll
        for (int r = 0; r < 4; ++r) {
          int t = rb + r;
          float v = acc[i][j][r] + bs;
          if (MODE == 0)      ((u16*)C)[(size_t)t * N + n] = f2bf(v);
          else                ((float*)C)[(size_t)t * N + n] = v;
        }
      }
    }
  }
}

// ================= gemm128f8: MX-fp8, same structure, BK=128 =================
// C[t,n] = sum_k A[t,k]*B[n,k], A/B fp8 e4m3, unit MX scales.
// MODE 0: bf16 out, v*episcale (+bias if given).
// MODE 2: conv A-addressing (A = fp8 Qpad halo), epilogue gelu(silu(v+bias)) -> fp8 out.
template<int MODE>
__global__ __launch_bounds__(256, 2)
void gemm128f8(const u8* __restrict__ A, const u8* __restrict__ B,
               void* __restrict__ C, const float* __restrict__ bias, float episcale,
               int M, int N, int K, int lda /*bytes*/)
{
  __shared__ alignas(16) char smem[32768];
  char* sA = smem;
  char* sB = smem + 16384;

  int nwg = gridDim.x;
  int bx = blockIdx.x;
  if ((nwg & 7) == 0) bx = (bx & 7) * (nwg >> 3) + (bx >> 3);
  int GN = N >> 7;
  int bm = bx / GN, bn = bx - bm * GN;
  int m0 = bm << 7, n0 = bn << 7;

  int tid = threadIdx.x;
  int lane = tid & 63, wid = tid >> 6;
  int wm = wid >> 1, wn = wid & 1;

  f32x4 acc[4][4] = {};

  int strow = tid >> 3;            // 0..31
  int stcolb = (tid & 7) << 4;     // byte col 0..112 within 128B row
  int bofm = m0 >> 12;

  const int KT = K >> 7;           // BK = 128 (bytes == elements)
  for (int kt = 0; kt < KT; ++kt) {
    int k0 = kt << 7;
    const char* Ab;
    if (MODE == 2) {
      int tap = k0 >> 10;          // K = 3072 = 3 taps x 1024
      Ab = (const char*)A + (size_t)(m0 + 2 * bofm + tap) * lda + (k0 & 1023);
    } else {
      Ab = (const char*)A + (size_t)m0 * lda + k0;
    }
    const char* Bb = (const char*)B + (size_t)n0 * K + k0;
#pragma unroll
    for (int j = 0; j < 4; ++j) {
      int row = j * 32 + strow;
      int sw = (row & 7) << 4;
      gload_lds16(Ab + (size_t)row * lda + (size_t)(stcolb ^ sw), sA + j * 4096 + wid * 1024);
      gload_lds16(Bb + (size_t)row * K + (size_t)(stcolb ^ sw), sB + j * 4096 + wid * 1024);
    }
    __syncthreads();
    {
      i32x8 av[4], bv[4];
      int cb = (lane >> 4) << 5;   // 32B K-chunk per lane group (one MX block)
#pragma unroll
      for (int i = 0; i < 4; ++i) {
        int r = (wm << 6) + (i << 4) + (lane & 15);
        int sw = (r & 7) << 4;
        i32x4 lo = *(const i32x4*)(sA + r * 128 + (cb ^ sw));
        i32x4 hi = *(const i32x4*)(sA + r * 128 + ((cb + 16) ^ sw));
        av[i] = i32x8{lo[0], lo[1], lo[2], lo[3], hi[0], hi[1], hi[2], hi[3]};
      }
#pragma unroll
      for (int j = 0; j < 4; ++j) {
        int r = (wn << 6) + (j << 4) + (lane & 15);
        int sw = (r & 7) << 4;
        i32x4 lo = *(const i32x4*)(sB + r * 128 + (cb ^ sw));
        i32x4 hi = *(const i32x4*)(sB + r * 128 + ((cb + 16) ^ sw));
        bv[j] = i32x8{lo[0], lo[1], lo[2], lo[3], hi[0], hi[1], hi[2], hi[3]};
      }
#pragma unroll
      for (int i = 0; i < 4; ++i)
#pragma unroll
        for (int j = 0; j < 4; ++j)
          acc[i][j] = mfma_mx(av[i], bv[j], acc[i][j]);
    }
    __syncthreads();
  }

  // epilogue
#pragma unroll
  for (int i = 0; i < 4; ++i) {
    int rb = m0 + (wm << 6) + (i << 4) + ((lane >> 4) << 2);
#pragma unroll
    for (int j = 0; j < 4; ++j) {
      int n = n0 + (wn << 6) + (j << 4) + (lane & 15);
      float bs = bias ? bias[n] : 0.f;
#pragma unroll
      for (int r = 0; r < 4; ++r) {
        int t = rb + r;
        float v = acc[i][j][r] + bs;
        if (MODE == 0)  ((u16*)C)[(size_t)t * N + n] = f2bf(v * episcale);
        else            ((u8*)C)[(size_t)t * N + n] = f2fp8(geluf(siluf(v)));
      }
    }
  }
}

// ---------------- softmax-weighted column sum ----------------
__global__ void summ_partial(const u16* __restrict__ logits, const u16* __restrict__ vals,
                             float* __restrict__ pm, float* __restrict__ pz,
                             float* __restrict__ pn)
{
  int tid = threadIdx.x;
  int sc = blockIdx.x, ec = blockIdx.y, b = blockIdx.z;
  int e = ec * 256 + tid;
  float m = -1e30f, z = 0.f, num = 0.f;
  int t0 = b * 4096 + sc * 128;
  for (int si = 0; si < 128; ++si) {
    int t = t0 + si;
    float l = bf2f(logits[(size_t)t * 1024 + e]);
    float v = bf2f(vals[(size_t)t * 1024 + e]);
    float mn = fmaxf(m, l);
    float cc = __expf(m - mn);
    float p = __expf(l - mn);
    z = z * cc + p;
    num = num * cc + v * p;
    m = mn;
  }
  int pidx = (((b * 4 + ec) * 32) + sc) * 256 + tid;
  pm[pidx] = m; pz[pidx] = z; pn[pidx] = num;
}

// summ = (num/Z) * (mul ? mul : 1)
__global__ void summ_combine(const float* __restrict__ pm, const float* __restrict__ pz,
                             const float* __restrict__ pn, const float* __restrict__ mul,
                             float* __restrict__ summ)
{
  int idx = blockIdx.x * 256 + threadIdx.x;  // 0..4095 : b*1024+e
  int b = idx >> 10, e = idx & 1023;
  int ec = e >> 8, tt = e & 255;
  const int base = ((b * 4 + ec) * 32) * 256 + tt;
  float M = -1e30f;
  for (int sc = 0; sc < 32; ++sc) M = fmaxf(M, pm[base + sc * 256]);
  float Z = 0.f, Nm = 0.f;
  for (int sc = 0; sc < 32; ++sc) {
    float w = __expf(pm[base + sc * 256] - M);
    Z += pz[base + sc * 256] * w;
    Nm += pn[base + sc * 256] * w;
  }
  float r = Nm / Z;
  summ[idx] = mul ? r * mul[idx] : r;
}

// ---------------- elementwise ----------------
// GP8 = fp8(gelu(O * s1[b,:]))
__global__ void pk(const u16* __restrict__ O, const float* __restrict__ s1,
                   u8* __restrict__ GP8)
{
  size_t idx = (size_t)blockIdx.x * 256 + threadIdx.x;
  size_t base = idx * 8;
  int t = (int)(base >> 10);
  int b = t >> 12;
  int e = (int)(base & 1023);
  const float* sp = s1 + b * 1024 + e;
  u16x8 ov = *(const u16x8*)(O + base);
  u8x8 gv;
#pragma unroll
  for (int j = 0; j < 8; ++j) {
    gv[j] = f2fp8(geluf(bf2f(ov[j]) * sp[j]));
  }
  *(u8x8*)(GP8 + base) = gv;
}

// L = silu(G) * summ2[b,:]
__global__ void lk(const u16* __restrict__ G, const float* __restrict__ s2,
                   u16* __restrict__ L)
{
  size_t idx = (size_t)blockIdx.x * 256 + threadIdx.x;
  size_t base = idx * 8;
  int t = (int)(base >> 10);
  int b = t >> 12;
  int e = (int)(base & 1023);
  const float* sp = s2 + b * 1024 + e;
  u16x8 gvv = *(const u16x8*)(G + base);
  u16x8 lv;
#pragma unroll
  for (int j = 0; j < 8; ++j) {
    lv[j] = f2bf(siluf(bf2f(gvv[j])) * sp[j]);
  }
  *(u16x8*)(L + base) = lv;
}

// ---------------- launch ----------------
extern "C" void kernel_launch(void* const* d_in, const int* in_sizes, int n_in,
                              void* d_out, int out_size, void* d_ws, size_t ws_size,
                              hipStream_t stream)
{
  const float* x     = (const float*)d_in[0];
  const float* Wq    = (const float*)d_in[1];
  const float* Wqb   = (const float*)d_in[2];
  const float* Wo    = (const float*)d_in[3];
  const float* Wob   = (const float*)d_in[4];
  const float* Wg    = (const float*)d_in[5];
  const float* Wgb   = (const float*)d_in[6];
  const float* wa    = (const float*)d_in[7];
  const float* wb    = (const float*)d_in[8];
  const float* Wout  = (const float*)d_in[9];
  const float* Woutb = (const float*)d_in[10];
  const float* convw = (const float*)d_in[11];
  const float* convb = (const float*)d_in[12];

  char* ws = (char*)d_ws;
  size_t off = 0;
  auto alloc = [&](size_t bytes) -> char* {
    char* p = ws + off;
    off += (bytes + 255) & ~(size_t)255;
    return p;
  };

  u8*  QPAD8 = (u8*)alloc((size_t)4 * SPAD * 1024);       // fp8 Q, halo layout (conv A)
  u16* QB   = (u16*)alloc((size_t)NT * 1024 * 2);         // bf16 Q, plain (summ1 values)
  u16* OB   = (u16*)alloc((size_t)NT * 1024 * 2);         // O -> later L
  u16* GB   = (u16*)alloc((size_t)NT * 1024 * 2);         // G
  u16* XB   = (u16*)alloc((size_t)NT * 1024 * 2);         // x bf16 -> GA8 -> GP8
  u16* SS   = (u16*)alloc((size_t)NT * 1024 * 2);         // logits A -> logits B
  u16* WALL = (u16*)alloc((size_t)4 * 1024 * 1024 * 2);   // bf16 [Wq,Wo,Wg,Wout]
  u8*  WAB8 = (u8*)alloc((size_t)2 * 1024 * 1024);        // fp8 [wa, wb] (unscaled)
  u8*  WC8  = (u8*)alloc((size_t)1024 * 3072);            // fp8 conv weights
  float* PM = (float*)alloc((size_t)4 * 4 * 32 * 256 * 4);
  float* PZ = (float*)alloc((size_t)4 * 4 * 32 * 256 * 4);
  float* PN = (float*)alloc((size_t)4 * 4 * 32 * 256 * 4);
  float* S1 = (float*)alloc((size_t)4096 * 4);
  float* S2 = (float*)alloc((size_t)4096 * 4);

  if (off > ws_size) return;

  u16* WQOG   = WALL;                                 // [Wq,Wo,Wg] contiguous
  u16* WOUTB_ = WALL + (size_t)3 * 1048576;
  u8*  WA8    = WAB8;
  u8*  WB8    = WAB8 + (size_t)1048576;

  u8* GA8 = (u8*)XB;   // conv output fp8 (x dead after QOG)
  u8* GP8 = (u8*)XB;   // pk output fp8 (GA8 dead after wa-logits)
  u16* LB = OB;        // L aliases O (O dead after summ2 pass)

  const float scale = 0.03125f;  // 1/sqrt(1024)

  // 1. converts
  cvtk<<<16384, 256, 0, stream>>>(x, XB, 4194304, 1.0f);
  cvtw4<<<4096, 256, 0, stream>>>(Wq, Wo, Wg, Wout, WALL);
  cvtw_f8<<<2048, 256, 0, stream>>>(wa, wb, WAB8);
  cvt_convw8<<<4096, 256, 0, stream>>>(convw, WC8);
  zero_halo8<<<32, 256, 0, stream>>>(QPAD8);

  // 2. fused Q/O/G GEMM (bf16): N=3072; Q -> QB(bf16) + QPAD8(fp8 halo)
  gemm128<4><<<128 * 24, 256, 0, stream>>>(XB, WQOG, QB, Wqb, OB, GB, QPAD8, Wob, Wgb,
                                           NT, 3072, 1024, 1024);

  // 3. conv as MX-fp8 GEMM (A = fp8 Qpad, K = 3072), epilogue gelu(silu(.)) -> GA8
  gemm128f8<2><<<128 * 8, 256, 0, stream>>>(QPAD8, WC8, GA8, convb, 1.0f,
                                            NT, 1024, 3072, 1024);

  // 4. logits A = (GA8 @ wa^T) * scale -> SS (bf16)
  gemm128f8<0><<<128 * 8, 256, 0, stream>>>(GA8, WA8, SS, nullptr, scale,
                                            NT, 1024, 1024, 1024);

  // 5. summ1 = softmax-weighted sum of Q (values = QB bf16)
  {
    dim3 g(32, 4, 4);
    summ_partial<<<g, 256, 0, stream>>>(SS, QB, PM, PZ, PN);
    summ_combine<<<16, 256, 0, stream>>>(PM, PZ, PN, nullptr, S1);
  }

  // 6. GP8 = fp8(gelu(O * summ1))
  pk<<<8192, 256, 0, stream>>>(OB, S1, GP8);

  // 7. logits B = (GP8 @ wb^T) * scale -> SS
  gemm128f8<0><<<128 * 8, 256, 0, stream>>>(GP8, WB8, SS, nullptr, scale,
                                            NT, 1024, 1024, 1024);

  // 8. summ2 = s1 * softmax-weighted sum of O
  {
    dim3 g(32, 4, 4);
    summ_partial<<<g, 256, 0, stream>>>(SS, OB, PM, PZ, PN);
    summ_combine<<<16, 256, 0, stream>>>(PM, PZ, PN, S1, S2);
  }

  // 9. L = silu(G) * summ2
  lk<<<8192, 256, 0, stream>>>(GB, S2, LB);

  // 10. out = L @ Wout^T + b  (bf16 GEMM, f32 out)
  gemm128<3><<<128 * 8, 256, 0, stream>>>(LB, WOUTB_, d_out, Woutb, nullptr, nullptr, nullptr,
                                          nullptr, nullptr, NT, 1024, 1024, 1024);
}

// Round 7
// 419.685 us; speedup vs baseline: 1.3072x; 1.0703x over previous
//
#include <hip/hip_runtime.h>
#include <stdint.h>

#define DEV __device__ __forceinline__

typedef unsigned short u16;
typedef unsigned int u32;
typedef unsigned char u8;

typedef __bf16 bf16x8 __attribute__((ext_vector_type(8)));
typedef float f32x4 __attribute__((ext_vector_type(4)));
typedef u16 u16x8 __attribute__((ext_vector_type(8)));
typedef u16 u16x4 __attribute__((ext_vector_type(4)));
typedef u8 u8x8 __attribute__((ext_vector_type(8)));
typedef int i32x4 __attribute__((ext_vector_type(4)));
typedef int i32x8 __attribute__((ext_vector_type(8)));

static_assert(sizeof(bf16x8) == 16, "bf16x8 must be 16B");

#define NT 16384      // B*S = 4*4096
#define SPAD 4098     // S + 2 halo rows per batch

DEV u16 f2bf(float f) {
  u32 u = __float_as_uint(f);
  u32 r = u + 0x7FFFu + ((u >> 16) & 1u);
  return (u16)(r >> 16);
}
DEV float bf2f(u16 h) { return __uint_as_float(((u32)h) << 16); }
DEV float siluf(float x) { return x / (1.f + __expf(-x)); }
DEV float geluf(float x) { return 0.5f * x * (1.f + erff(x * 0.70710678118654752f)); }

// float -> OCP e4m3fn (RNE for normals, half-up for subnormals, clamp to 448)
DEV u8 f2fp8(float f) {
  u32 u = __float_as_uint(f);
  u32 s = (u >> 24) & 0x80u;
  u32 a = u & 0x7FFFFFFFu;
  if (a >= 0x43E00000u) return (u8)(s | 0x7E);      // >= 448 -> max finite
  if (a < 0x3C800000u) {                             // < 2^-6 -> subnormal (step 2^-9)
    float q = __uint_as_float(a) * 512.f;
    u32 m = (u32)(q + 0.5f);                         // 0..8 (8 carries to min normal)
    return (u8)(s | m);
  }
  u32 r = a + 0xFFFFFu + ((a >> 20) & 1u);           // RNE to 3 mantissa bits
  if (r >= 0x43E00000u) return (u8)(s | 0x7E);
  u32 e = (r >> 23) - 120u;                          // biased-7 exponent, 1..15
  u32 m = (r >> 20) & 7u;
  return (u8)(s | (e << 3) | m);
}

DEV void gload_lds16(const void* g, void* l) {
  __builtin_amdgcn_global_load_lds((const __attribute__((address_space(1))) void*)g,
                                   (__attribute__((address_space(3))) void*)l,
                                   16, 0, 0);
}

DEV f32x4 mfma_mx(i32x8 a, i32x8 b, f32x4 c) {
  // fp8(e4m3) x fp8, unit scales (E8M0 127 = 2^0) -> scale-block mapping irrelevant
  return __builtin_amdgcn_mfma_scale_f32_16x16x128_f8f6f4(
      a, b, c, 0, 0, 0, 0x7F7F7F7Fu, 0, 0x7F7F7F7Fu);
}

// ---------------- converts ----------------
__global__ void cvtk(const float* __restrict__ in, u16* __restrict__ out, int n4, float scale) {
  int i = blockIdx.x * 256 + threadIdx.x;
  if (i >= n4) return;
  const float4 v = *(const float4*)(in + (size_t)i * 4);
  u16x4 o;
  o[0] = f2bf(v.x * scale); o[1] = f2bf(v.y * scale);
  o[2] = f2bf(v.z * scale); o[3] = f2bf(v.w * scale);
  *(u16x4*)(out + (size_t)i * 4) = o;
}

// 4 d*d weight matrices -> one contiguous bf16 buffer [Wq,Wo,Wg,Wout]
__global__ void cvtw4(const float* __restrict__ w0, const float* __restrict__ w1,
                      const float* __restrict__ w2, const float* __restrict__ w3,
                      u16* __restrict__ dst) {
  int idx = blockIdx.x * 256 + threadIdx.x;      // 4 * 262144 four-elem groups
  int mat = idx >> 18, within = idx & 262143;
  const float* src = (mat == 0) ? w0 : (mat == 1) ? w1 : (mat == 2) ? w2 : w3;
  const float4 v = *(const float4*)(src + (size_t)within * 4);
  u16x4 o;
  o[0] = f2bf(v.x); o[1] = f2bf(v.y); o[2] = f2bf(v.z); o[3] = f2bf(v.w);
  *(u16x4*)(dst + (size_t)idx * 4) = o;
}

// wa, wb -> fp8 (UNscaled; 1/32 logit scale applied in GEMM epilogue)
__global__ void cvtw_f8(const float* __restrict__ wa, const float* __restrict__ wb,
                        u8* __restrict__ dst) {
  int idx = blockIdx.x * 256 + threadIdx.x;      // 2 * 262144
  const float* src = (idx >> 18) ? wb : wa;
  int within = idx & 262143;
  const float4 v = *(const float4*)(src + (size_t)within * 4);
  u32 o = (u32)f2fp8(v.x) | ((u32)f2fp8(v.y) << 8) |
          ((u32)f2fp8(v.z) << 16) | ((u32)f2fp8(v.w) << 24);
  *(u32*)(dst + (size_t)idx * 4) = o;
}

// conv_w [o][d][3] -> fp8 Wc [o][tap*1024 + d]
__global__ void cvt_convw8(const float* __restrict__ cw, u8* __restrict__ Wc) {
  int i = blockIdx.x * 256 + threadIdx.x;   // 1M threads: o*1024+d
  int o = i >> 10, d = i & 1023;
  const float* src = cw + ((size_t)o * 1024 + d) * 3;
  u8* dst = Wc + (size_t)o * 3072 + d;
  dst[0]    = f2fp8(src[0]);
  dst[1024] = f2fp8(src[1]);
  dst[2048] = f2fp8(src[2]);
}

// zero the 2 halo rows of each batch in bf16 Qpad
__global__ void zero_halo(u16* __restrict__ Qpad) {
  int i = blockIdx.x * 256 + threadIdx.x;   // 8192 threads
  int r = i >> 10, c = i & 1023;
  int b = r >> 1, side = r & 1;
  size_t row = (size_t)b * SPAD + (side ? (SPAD - 1) : 0);
  Qpad[row * 1024 + c] = 0;
}

// bf16 halo Qpad -> fp8 halo Qpad8 (linear, includes halo rows)
__global__ void cvt_q8(const u16* __restrict__ Qpad, u8* __restrict__ Qpad8) {
  size_t idx = (size_t)blockIdx.x * 256 + threadIdx.x;   // 2,098,176 threads x 8 elems
  size_t base = idx * 8;
  u16x8 v = *(const u16x8*)(Qpad + base);
  u8x8 o;
#pragma unroll
  for (int j = 0; j < 8; ++j) o[j] = f2fp8(bf2f(v[j]));
  *(u8x8*)(Qpad8 + base) = o;
}

// ================= gemm128: PROVEN bf16 structure (~888 TF) =================
// MODE 3: f32 out (+bias). MODE 4: QOG fused, seg=n>>10: Q->C (bf16 halo remap); O->C2; G->C3.
template<int MODE>
__global__ __launch_bounds__(256, 2)
void gemm128(const u16* __restrict__ A, const u16* __restrict__ B,
             void* __restrict__ C, const float* __restrict__ bias,
             void* __restrict__ C2, void* __restrict__ C3,
             const float* __restrict__ bias2, const float* __restrict__ bias3,
             int M, int N, int K, int lda)
{
  __shared__ alignas(16) char smem[32768];
  char* sA = smem;
  char* sB = smem + 16384;

  int nwg = gridDim.x;
  int bx = blockIdx.x;
  if ((nwg & 7) == 0) bx = (bx & 7) * (nwg >> 3) + (bx >> 3);  // XCD swizzle (bijective)
  int GN = N >> 7;
  int bm = bx / GN, bn = bx - bm * GN;
  int m0 = bm << 7, n0 = bn << 7;

  int tid = threadIdx.x;
  int lane = tid & 63, wid = tid >> 6;
  int wm = wid >> 1, wn = wid & 1;

  f32x4 acc[4][4] = {};

  int strow = tid >> 3;            // 0..31
  int stcolb = (tid & 7) << 4;     // byte col 0..112
  size_t ldab = (size_t)lda * 2;
  size_t ldbb = (size_t)K * 2;

  const int KT = K >> 6;
  for (int kt = 0; kt < KT; ++kt) {
    int k0 = kt << 6;
    const char* Ab = (const char*)(A + ((size_t)m0 * (size_t)lda + k0));
    const char* Bb = (const char*)(B + ((size_t)n0 * (size_t)K + k0));
#pragma unroll
    for (int j = 0; j < 4; ++j) {
      int row = j * 32 + strow;
      int sw = (row & 7) << 4;     // XOR swizzle on 16B granules (involution)
      gload_lds16(Ab + (size_t)row * ldab + (size_t)(stcolb ^ sw), sA + j * 4096 + wid * 1024);
      gload_lds16(Bb + (size_t)row * ldbb + (size_t)(stcolb ^ sw), sB + j * 4096 + wid * 1024);
    }
    __syncthreads();
#pragma unroll
    for (int kk = 0; kk < 2; ++kk) {
      bf16x8 av[4], bv[4];
      int cb = ((lane >> 4) << 4) + (kk << 6);
#pragma unroll
      for (int i = 0; i < 4; ++i) {
        int r = (wm << 6) + (i << 4) + (lane & 15);
        av[i] = *(const bf16x8*)(sA + r * 128 + (cb ^ ((r & 7) << 4)));
      }
#pragma unroll
      for (int j = 0; j < 4; ++j) {
        int r = (wn << 6) + (j << 4) + (lane & 15);
        bv[j] = *(const bf16x8*)(sB + r * 128 + (cb ^ ((r & 7) << 4)));
      }
#pragma unroll
      for (int i = 0; i < 4; ++i)
#pragma unroll
        for (int j = 0; j < 4; ++j)
          acc[i][j] = __builtin_amdgcn_mfma_f32_16x16x32_bf16(av[i], bv[j], acc[i][j], 0, 0, 0);
    }
    __syncthreads();
  }

  // epilogue: frag row=(lane>>4)*4+r, col=lane&15
#pragma unroll
  for (int i = 0; i < 4; ++i) {
    int rb = m0 + (wm << 6) + (i << 4) + ((lane >> 4) << 2);
#pragma unroll
    for (int j = 0; j < 4; ++j) {
      int n = n0 + (wn << 6) + (j << 4) + (lane & 15);
      if (MODE == 4) {
        int seg = n >> 10, nn = n & 1023;    // seg is block-uniform (128 | 1024)
        const float* bsel = (seg == 0) ? bias : ((seg == 1) ? bias2 : bias3);
        float bs = bsel ? bsel[nn] : 0.f;
#pragma unroll
        for (int r = 0; r < 4; ++r) {
          int t = rb + r;
          u16 h = f2bf(acc[i][j][r] + bs);
          if (seg == 0) {
            size_t row = (size_t)t + 2 * (t >> 12) + 1;   // Q -> bf16 halo remap
            ((u16*)C)[row * 1024 + nn] = h;
          } else if (seg == 1) {
            ((u16*)C2)[(size_t)t * 1024 + nn] = h;
          } else {
            ((u16*)C3)[(size_t)t * 1024 + nn] = h;
          }
        }
      } else {
        float bs = bias ? bias[n] : 0.f;
#pragma unroll
        for (int r = 0; r < 4; ++r) {
          int t = rb + r;
          float v = acc[i][j][r] + bs;
          ((float*)C)[(size_t)t * N + n] = v;
        }
      }
    }
  }
}

// ================= gemm128f8: MX-fp8, same structure, BK=128 =================
// MODE 2: conv A-addressing (A = fp8 Qpad halo), epilogue gelu(silu(v+bias)) -> fp8 out.
// MODE 5: fused logits+softmax-partial: w = exp(acc*episcale); reads vals tile
//         (VREMAP: halo row remap), reduces per-column over block, writes
//         PZp/PNp[m_tile][col]. No C output.
template<int MODE, int VREMAP>
__global__ __launch_bounds__(256, 2)
void gemm128f8(const u8* __restrict__ A, const u8* __restrict__ B,
               void* __restrict__ C, const float* __restrict__ bias, float episcale,
               const u16* __restrict__ vals, float* __restrict__ PZp, float* __restrict__ PNp,
               int M, int N, int K, int lda /*bytes*/)
{
  __shared__ alignas(16) char smem[32768];
  char* sA = smem;
  char* sB = smem + 16384;

  int nwg = gridDim.x;
  int bx = blockIdx.x;
  if ((nwg & 7) == 0) bx = (bx & 7) * (nwg >> 3) + (bx >> 3);
  int GN = N >> 7;
  int bm = bx / GN, bn = bx - bm * GN;
  int m0 = bm << 7, n0 = bn << 7;

  int tid = threadIdx.x;
  int lane = tid & 63, wid = tid >> 6;
  int wm = wid >> 1, wn = wid & 1;

  f32x4 acc[4][4] = {};

  int strow = tid >> 3;            // 0..31
  int stcolb = (tid & 7) << 4;     // byte col 0..112 within 128B row
  int bofm = m0 >> 12;

  const int KT = K >> 7;           // BK = 128 (bytes == elements)
  for (int kt = 0; kt < KT; ++kt) {
    int k0 = kt << 7;
    const char* Ab;
    if (MODE == 2) {
      int tap = k0 >> 10;          // K = 3072 = 3 taps x 1024
      Ab = (const char*)A + (size_t)(m0 + 2 * bofm + tap) * lda + (k0 & 1023);
    } else {
      Ab = (const char*)A + (size_t)m0 * lda + k0;
    }
    const char* Bb = (const char*)B + (size_t)n0 * K + k0;
#pragma unroll
    for (int j = 0; j < 4; ++j) {
      int row = j * 32 + strow;
      int sw = (row & 7) << 4;
      gload_lds16(Ab + (size_t)row * lda + (size_t)(stcolb ^ sw), sA + j * 4096 + wid * 1024);
      gload_lds16(Bb + (size_t)row * K + (size_t)(stcolb ^ sw), sB + j * 4096 + wid * 1024);
    }
    __syncthreads();
    {
      i32x8 av[4], bv[4];
      int cb = (lane >> 4) << 5;   // 32B K-chunk per lane group (one MX block)
#pragma unroll
      for (int i = 0; i < 4; ++i) {
        int r = (wm << 6) + (i << 4) + (lane & 15);
        int sw = (r & 7) << 4;
        i32x4 lo = *(const i32x4*)(sA + r * 128 + (cb ^ sw));
        i32x4 hi = *(const i32x4*)(sA + r * 128 + ((cb + 16) ^ sw));
        av[i] = i32x8{lo[0], lo[1], lo[2], lo[3], hi[0], hi[1], hi[2], hi[3]};
      }
#pragma unroll
      for (int j = 0; j < 4; ++j) {
        int r = (wn << 6) + (j << 4) + (lane & 15);
        int sw = (r & 7) << 4;
        i32x4 lo = *(const i32x4*)(sB + r * 128 + (cb ^ sw));
        i32x4 hi = *(const i32x4*)(sB + r * 128 + ((cb + 16) ^ sw));
        bv[j] = i32x8{lo[0], lo[1], lo[2], lo[3], hi[0], hi[1], hi[2], hi[3]};
      }
#pragma unroll
      for (int i = 0; i < 4; ++i)
#pragma unroll
        for (int j = 0; j < 4; ++j)
          acc[i][j] = mfma_mx(av[i], bv[j], acc[i][j]);
    }
    __syncthreads();
  }

  if (MODE == 2) {
#pragma unroll
    for (int i = 0; i < 4; ++i) {
      int rb = m0 + (wm << 6) + (i << 4) + ((lane >> 4) << 2);
#pragma unroll
      for (int j = 0; j < 4; ++j) {
        int n = n0 + (wn << 6) + (j << 4) + (lane & 15);
        float bs = bias ? bias[n] : 0.f;
#pragma unroll
        for (int r = 0; r < 4; ++r) {
          int t = rb + r;
          float v = acc[i][j][r] + bs;
          ((u8*)C)[(size_t)t * N + n] = f2fp8(geluf(siluf(v)));
        }
      }
    }
  } else {  // MODE 5: fused softmax partial (no max subtraction; logits are tiny)
    float zj[4] = {0.f, 0.f, 0.f, 0.f}, nj[4] = {0.f, 0.f, 0.f, 0.f};
#pragma unroll
    for (int i = 0; i < 4; ++i) {
      int rb = m0 + (wm << 6) + (i << 4) + ((lane >> 4) << 2);
#pragma unroll
      for (int j = 0; j < 4; ++j) {
        int n = n0 + (wn << 6) + (j << 4) + (lane & 15);
#pragma unroll
        for (int r = 0; r < 4; ++r) {
          int t = rb + r;
          float w = __expf(acc[i][j][r] * episcale);
          size_t vrow = VREMAP ? ((size_t)t + 2 * (t >> 12) + 1) : (size_t)t;
          float v = bf2f(vals[vrow * 1024 + n]);
          zj[j] += w;
          nj[j] += v * w;
        }
      }
    }
    __syncthreads();                 // LDS free after K-loop's trailing sync + this
    float2* arr = (float2*)smem;     // [128 cols][8 contributors]
    int g = (wm << 2) + (lane >> 4); // 0..7
#pragma unroll
    for (int j = 0; j < 4; ++j) {
      int cl = (wn << 6) + (j << 4) + (lane & 15);   // 0..127
      arr[cl * 8 + g] = make_float2(zj[j], nj[j]);
    }
    __syncthreads();
    if (tid < 128) {
      float Z = 0.f, Nn = 0.f;
#pragma unroll
      for (int g2 = 0; g2 < 8; ++g2) { float2 p = arr[tid * 8 + g2]; Z += p.x; Nn += p.y; }
      size_t o = (size_t)(m0 >> 7) * 1024 + n0 + tid;
      PZp[o] = Z;
      PNp[o] = Nn;
    }
  }
}

// ---------------- combine: summ = (sum PN / sum PZ) * (mul ? mul : 1) ----------------
__global__ void summ_combine(const float* __restrict__ pz, const float* __restrict__ pn,
                             const float* __restrict__ mul, float* __restrict__ summ)
{
  int idx = blockIdx.x * 256 + threadIdx.x;  // 0..4095 : b*1024+e
  int b = idx >> 10, e = idx & 1023;
  float Z = 0.f, Nn = 0.f;
  for (int bm = b * 32; bm < b * 32 + 32; ++bm) {
    Z += pz[(size_t)bm * 1024 + e];
    Nn += pn[(size_t)bm * 1024 + e];
  }
  float r = Nn / Z;
  summ[idx] = mul ? r * mul[idx] : r;
}

// ---------------- elementwise ----------------
// GP8 = fp8(gelu(O * s1[b,:]))
__global__ void pk(const u16* __restrict__ O, const float* __restrict__ s1,
                   u8* __restrict__ GP8)
{
  size_t idx = (size_t)blockIdx.x * 256 + threadIdx.x;
  size_t base = idx * 8;
  int t = (int)(base >> 10);
  int b = t >> 12;
  int e = (int)(base & 1023);
  const float* sp = s1 + b * 1024 + e;
  u16x8 ov = *(const u16x8*)(O + base);
  u8x8 gv;
#pragma unroll
  for (int j = 0; j < 8; ++j) {
    gv[j] = f2fp8(geluf(bf2f(ov[j]) * sp[j]));
  }
  *(u8x8*)(GP8 + base) = gv;
}

// L = silu(G) * summ2[b,:]
__global__ void lk(const u16* __restrict__ G, const float* __restrict__ s2,
                   u16* __restrict__ L)
{
  size_t idx = (size_t)blockIdx.x * 256 + threadIdx.x;
  size_t base = idx * 8;
  int t = (int)(base >> 10);
  int b = t >> 12;
  int e = (int)(base & 1023);
  const float* sp = s2 + b * 1024 + e;
  u16x8 gvv = *(const u16x8*)(G + base);
  u16x8 lv;
#pragma unroll
  for (int j = 0; j < 8; ++j) {
    lv[j] = f2bf(siluf(bf2f(gvv[j])) * sp[j]);
  }
  *(u16x8*)(L + base) = lv;
}

// ---------------- launch ----------------
extern "C" void kernel_launch(void* const* d_in, const int* in_sizes, int n_in,
                              void* d_out, int out_size, void* d_ws, size_t ws_size,
                              hipStream_t stream)
{
  const float* x     = (const float*)d_in[0];
  const float* Wq    = (const float*)d_in[1];
  const float* Wqb   = (const float*)d_in[2];
  const float* Wo    = (const float*)d_in[3];
  const float* Wob   = (const float*)d_in[4];
  const float* Wg    = (const float*)d_in[5];
  const float* Wgb   = (const float*)d_in[6];
  const float* wa    = (const float*)d_in[7];
  const float* wb    = (const float*)d_in[8];
  const float* Wout  = (const float*)d_in[9];
  const float* Woutb = (const float*)d_in[10];
  const float* convw = (const float*)d_in[11];
  const float* convb = (const float*)d_in[12];

  char* ws = (char*)d_ws;
  size_t off = 0;
  auto alloc = [&](size_t bytes) -> char* {
    char* p = ws + off;
    off += (bytes + 255) & ~(size_t)255;
    return p;
  };

  u16* QPAD  = (u16*)alloc((size_t)4 * SPAD * 1024 * 2);  // bf16 Q, halo layout
  u8*  QPAD8 = (u8*)alloc((size_t)4 * SPAD * 1024);       // fp8 Q, halo layout (conv A)
  u16* OB   = (u16*)alloc((size_t)NT * 1024 * 2);         // O -> later L
  u16* GB   = (u16*)alloc((size_t)NT * 1024 * 2);         // G
  u16* XB   = (u16*)alloc((size_t)NT * 1024 * 2);         // x bf16 -> GA8 -> GP8
  u16* WALL = (u16*)alloc((size_t)4 * 1024 * 1024 * 2);   // bf16 [Wq,Wo,Wg,Wout]
  u8*  WAB8 = (u8*)alloc((size_t)2 * 1024 * 1024);        // fp8 [wa, wb] (unscaled)
  u8*  WC8  = (u8*)alloc((size_t)1024 * 3072);            // fp8 conv weights
  float* PZb = (float*)alloc((size_t)128 * 1024 * 4);     // per-m-tile softmax partials
  float* PNb = (float*)alloc((size_t)128 * 1024 * 4);
  float* S1 = (float*)alloc((size_t)4096 * 4);
  float* S2 = (float*)alloc((size_t)4096 * 4);

  if (off > ws_size) return;

  u16* WQOG   = WALL;                                 // [Wq,Wo,Wg] contiguous
  u16* WOUTB_ = WALL + (size_t)3 * 1048576;
  u8*  WA8    = WAB8;
  u8*  WB8    = WAB8 + (size_t)1048576;

  u8* GA8 = (u8*)XB;   // conv output fp8 (x dead after QOG)
  u8* GP8 = (u8*)XB;   // pk output fp8 (GA8 dead after wa-logits)
  u16* LB = OB;        // L aliases O (O dead after wb pass)

  const float scale = 0.03125f;  // 1/sqrt(1024)

  // 1. converts
  cvtk<<<16384, 256, 0, stream>>>(x, XB, 4194304, 1.0f);
  cvtw4<<<4096, 256, 0, stream>>>(Wq, Wo, Wg, Wout, WALL);
  cvtw_f8<<<2048, 256, 0, stream>>>(wa, wb, WAB8);
  cvt_convw8<<<4096, 256, 0, stream>>>(convw, WC8);
  zero_halo<<<32, 256, 0, stream>>>(QPAD);

  // 2. fused Q/O/G GEMM (bf16, r5 epilogue): Q -> QPAD bf16 halo; O; G
  gemm128<4><<<128 * 24, 256, 0, stream>>>(XB, WQOG, QPAD, Wqb, OB, GB, Wob, Wgb,
                                           NT, 3072, 1024, 1024);

  // 2b. Q bf16 halo -> fp8 halo (linear copy incl. zero halos)
  cvt_q8<<<8196, 256, 0, stream>>>(QPAD, QPAD8);

  // 3. conv as MX-fp8 GEMM (A = fp8 Qpad, K = 3072), epilogue gelu(silu(.)) -> GA8
  gemm128f8<2, 0><<<128 * 8, 256, 0, stream>>>(QPAD8, WC8, GA8, convb, 1.0f,
                                               nullptr, nullptr, nullptr,
                                               NT, 1024, 3072, 1024);

  // 4+5a. logits A + fused softmax partials (vals = QPAD bf16, halo remap)
  gemm128f8<5, 1><<<128 * 8, 256, 0, stream>>>(GA8, WA8, nullptr, nullptr, scale,
                                               QPAD, PZb, PNb,
                                               NT, 1024, 1024, 1024);
  summ_combine<<<16, 256, 0, stream>>>(PZb, PNb, nullptr, S1);

  // 6. GP8 = fp8(gelu(O * summ1))
  pk<<<8192, 256, 0, stream>>>(OB, S1, GP8);

  // 7+8a. logits B + fused softmax partials (vals = OB plain)
  gemm128f8<5, 0><<<128 * 8, 256, 0, stream>>>(GP8, WB8, nullptr, nullptr, scale,
                                               OB, PZb, PNb,
                                               NT, 1024, 1024, 1024);
  summ_combine<<<16, 256, 0, stream>>>(PZb, PNb, S1, S2);

  // 9. L = silu(G) * summ2
  lk<<<8192, 256, 0, stream>>>(GB, S2, LB);

  // 10. out = L @ Wout^T + b  (bf16 GEMM, f32 out)
  gemm128<3><<<128 * 8, 256, 0, stream>>>(LB, WOUTB_, d_out, Woutb, nullptr, nullptr,
                                          nullptr, nullptr, NT, 1024, 1024, 1024);
}

// Round 8
// 412.399 us; speedup vs baseline: 1.3303x; 1.0177x over previous
//
#include <hip/hip_runtime.h>
#include <stdint.h>

#define DEV __device__ __forceinline__

typedef unsigned short u16;
typedef unsigned int u32;
typedef unsigned char u8;

typedef __bf16 bf16x8 __attribute__((ext_vector_type(8)));
typedef float f32x4 __attribute__((ext_vector_type(4)));
typedef u16 u16x8 __attribute__((ext_vector_type(8)));
typedef u16 u16x4 __attribute__((ext_vector_type(4)));
typedef u8 u8x8 __attribute__((ext_vector_type(8)));
typedef int i32x4 __attribute__((ext_vector_type(4)));
typedef int i32x8 __attribute__((ext_vector_type(8)));

static_assert(sizeof(bf16x8) == 16, "bf16x8 must be 16B");

#define NT 16384      // B*S = 4*4096
#define SPAD 4098     // S + 2 halo rows per batch

DEV u16 f2bf(float f) {
  u32 u = __float_as_uint(f);
  u32 r = u + 0x7FFFu + ((u >> 16) & 1u);
  return (u16)(r >> 16);
}
DEV float bf2f(u16 h) { return __uint_as_float(((u32)h) << 16); }
DEV float siluf(float x) { return x / (1.f + __expf(-x)); }
DEV float geluf(float x) { return 0.5f * x * (1.f + erff(x * 0.70710678118654752f)); }

// float -> OCP e4m3fn (RNE for normals, half-up for subnormals, clamp to 448)
DEV u8 f2fp8(float f) {
  u32 u = __float_as_uint(f);
  u32 s = (u >> 24) & 0x80u;
  u32 a = u & 0x7FFFFFFFu;
  if (a >= 0x43E00000u) return (u8)(s | 0x7E);      // >= 448 -> max finite
  if (a < 0x3C800000u) {                             // < 2^-6 -> subnormal (step 2^-9)
    float q = __uint_as_float(a) * 512.f;
    u32 m = (u32)(q + 0.5f);                         // 0..8 (8 carries to min normal)
    return (u8)(s | m);
  }
  u32 r = a + 0xFFFFFu + ((a >> 20) & 1u);           // RNE to 3 mantissa bits
  if (r >= 0x43E00000u) return (u8)(s | 0x7E);
  u32 e = (r >> 23) - 120u;                          // biased-7 exponent, 1..15
  u32 m = (r >> 20) & 7u;
  return (u8)(s | (e << 3) | m);
}

DEV void gload_lds16(const void* g, void* l) {
  __builtin_amdgcn_global_load_lds((const __attribute__((address_space(1))) void*)g,
                                   (__attribute__((address_space(3))) void*)l,
                                   16, 0, 0);
}

DEV f32x4 mfma_mx(i32x8 a, i32x8 b, f32x4 c) {
  // fp8(e4m3) x fp8, unit scales (E8M0 127 = 2^0) -> scale-block mapping irrelevant
  return __builtin_amdgcn_mfma_scale_f32_16x16x128_f8f6f4(
      a, b, c, 0, 0, 0, 0x7F7F7F7Fu, 0, 0x7F7F7F7Fu);
}

// ---------------- converts ----------------
__global__ void cvtk(const float* __restrict__ in, u16* __restrict__ out, int n4, float scale) {
  int i = blockIdx.x * 256 + threadIdx.x;
  if (i >= n4) return;
  const float4 v = *(const float4*)(in + (size_t)i * 4);
  u16x4 o;
  o[0] = f2bf(v.x * scale); o[1] = f2bf(v.y * scale);
  o[2] = f2bf(v.z * scale); o[3] = f2bf(v.w * scale);
  *(u16x4*)(out + (size_t)i * 4) = o;
}

// merged small converts: [0,4096): Wq/Wo/Wg/Wout -> bf16 WALL;
// [4096,6144): wa,wb -> fp8 WAB8; [6144,10240): conv_w -> fp8 WC8;
// [10240,10272): zero halo rows of bf16 QPAD.
__global__ void cvt_misc(const float* __restrict__ Wq, const float* __restrict__ Wo,
                         const float* __restrict__ Wg, const float* __restrict__ Wout,
                         const float* __restrict__ wa, const float* __restrict__ wb,
                         const float* __restrict__ cw,
                         u16* __restrict__ WALL, u8* __restrict__ WAB8,
                         u8* __restrict__ WC8, u16* __restrict__ QPAD)
{
  int bid = blockIdx.x, tid = threadIdx.x;
  if (bid < 4096) {
    int idx = bid * 256 + tid;                      // 4 * 262144 four-elem groups
    int mat = idx >> 18, within = idx & 262143;
    const float* src = (mat == 0) ? Wq : (mat == 1) ? Wo : (mat == 2) ? Wg : Wout;
    const float4 v = *(const float4*)(src + (size_t)within * 4);
    u16x4 o;
    o[0] = f2bf(v.x); o[1] = f2bf(v.y); o[2] = f2bf(v.z); o[3] = f2bf(v.w);
    *(u16x4*)(WALL + (size_t)idx * 4) = o;
  } else if (bid < 6144) {
    int idx = (bid - 4096) * 256 + tid;             // 2 * 262144
    const float* src = (idx >> 18) ? wb : wa;
    int within = idx & 262143;
    const float4 v = *(const float4*)(src + (size_t)within * 4);
    u32 o = (u32)f2fp8(v.x) | ((u32)f2fp8(v.y) << 8) |
            ((u32)f2fp8(v.z) << 16) | ((u32)f2fp8(v.w) << 24);
    *(u32*)(WAB8 + (size_t)idx * 4) = o;
  } else if (bid < 10240) {
    int i = (bid - 6144) * 256 + tid;               // 1M: o*1024+d
    int o = i >> 10, d = i & 1023;
    const float* src = cw + ((size_t)o * 1024 + d) * 3;
    u8* dst = WC8 + (size_t)o * 3072 + d;
    dst[0]    = f2fp8(src[0]);
    dst[1024] = f2fp8(src[1]);
    dst[2048] = f2fp8(src[2]);
  } else {
    int i = (bid - 10240) * 256 + tid;              // 8192 threads
    int r = i >> 10, c = i & 1023;
    int b = r >> 1, side = r & 1;
    size_t row = (size_t)b * SPAD + (side ? (SPAD - 1) : 0);
    QPAD[row * 1024 + c] = 0;
  }
}

// bf16 halo Qpad -> fp8 halo Qpad8 (linear, includes halo rows)
__global__ void cvt_q8(const u16* __restrict__ Qpad, u8* __restrict__ Qpad8) {
  size_t idx = (size_t)blockIdx.x * 256 + threadIdx.x;   // 2,098,176 x 8 elems
  size_t base = idx * 8;
  u16x8 v = *(const u16x8*)(Qpad + base);
  u8x8 o;
#pragma unroll
  for (int j = 0; j < 8; ++j) o[j] = f2fp8(bf2f(v[j]));
  *(u8x8*)(Qpad8 + base) = o;
}

// ================= gemm128: PROVEN bf16 structure (~888 TF) =================
// MODE 3: f32 out (+bias). MODE 4: QOG fused, seg=n>>10: Q->C (bf16 halo remap); O->C2; G->C3.
template<int MODE>
__global__ __launch_bounds__(256, 2)
void gemm128(const u16* __restrict__ A, const u16* __restrict__ B,
             void* __restrict__ C, const float* __restrict__ bias,
             void* __restrict__ C2, void* __restrict__ C3,
             const float* __restrict__ bias2, const float* __restrict__ bias3,
             int M, int N, int K, int lda)
{
  __shared__ alignas(16) char smem[32768];
  char* sA = smem;
  char* sB = smem + 16384;

  int nwg = gridDim.x;
  int bx = blockIdx.x;
  if ((nwg & 7) == 0) bx = (bx & 7) * (nwg >> 3) + (bx >> 3);  // XCD swizzle (bijective)
  int GN = N >> 7;
  int bm = bx / GN, bn = bx - bm * GN;
  int m0 = bm << 7, n0 = bn << 7;

  int tid = threadIdx.x;
  int lane = tid & 63, wid = tid >> 6;
  int wm = wid >> 1, wn = wid & 1;

  f32x4 acc[4][4] = {};

  int strow = tid >> 3;            // 0..31
  int stcolb = (tid & 7) << 4;     // byte col 0..112
  size_t ldab = (size_t)lda * 2;
  size_t ldbb = (size_t)K * 2;

  const int KT = K >> 6;
  for (int kt = 0; kt < KT; ++kt) {
    int k0 = kt << 6;
    const char* Ab = (const char*)(A + ((size_t)m0 * (size_t)lda + k0));
    const char* Bb = (const char*)(B + ((size_t)n0 * (size_t)K + k0));
#pragma unroll
    for (int j = 0; j < 4; ++j) {
      int row = j * 32 + strow;
      int sw = (row & 7) << 4;     // XOR swizzle on 16B granules (involution)
      gload_lds16(Ab + (size_t)row * ldab + (size_t)(stcolb ^ sw), sA + j * 4096 + wid * 1024);
      gload_lds16(Bb + (size_t)row * ldbb + (size_t)(stcolb ^ sw), sB + j * 4096 + wid * 1024);
    }
    __syncthreads();
#pragma unroll
    for (int kk = 0; kk < 2; ++kk) {
      bf16x8 av[4], bv[4];
      int cb = ((lane >> 4) << 4) + (kk << 6);
#pragma unroll
      for (int i = 0; i < 4; ++i) {
        int r = (wm << 6) + (i << 4) + (lane & 15);
        av[i] = *(const bf16x8*)(sA + r * 128 + (cb ^ ((r & 7) << 4)));
      }
#pragma unroll
      for (int j = 0; j < 4; ++j) {
        int r = (wn << 6) + (j << 4) + (lane & 15);
        bv[j] = *(const bf16x8*)(sB + r * 128 + (cb ^ ((r & 7) << 4)));
      }
#pragma unroll
      for (int i = 0; i < 4; ++i)
#pragma unroll
        for (int j = 0; j < 4; ++j)
          acc[i][j] = __builtin_amdgcn_mfma_f32_16x16x32_bf16(av[i], bv[j], acc[i][j], 0, 0, 0);
    }
    __syncthreads();
  }

  // epilogue: frag row=(lane>>4)*4+r, col=lane&15
#pragma unroll
  for (int i = 0; i < 4; ++i) {
    int rb = m0 + (wm << 6) + (i << 4) + ((lane >> 4) << 2);
#pragma unroll
    for (int j = 0; j < 4; ++j) {
      int n = n0 + (wn << 6) + (j << 4) + (lane & 15);
      if (MODE == 4) {
        int seg = n >> 10, nn = n & 1023;    // seg is block-uniform (128 | 1024)
        const float* bsel = (seg == 0) ? bias : ((seg == 1) ? bias2 : bias3);
        float bs = bsel ? bsel[nn] : 0.f;
#pragma unroll
        for (int r = 0; r < 4; ++r) {
          int t = rb + r;
          u16 h = f2bf(acc[i][j][r] + bs);
          if (seg == 0) {
            size_t row = (size_t)t + 2 * (t >> 12) + 1;   // Q -> bf16 halo remap
            ((u16*)C)[row * 1024 + nn] = h;
          } else if (seg == 1) {
            ((u16*)C2)[(size_t)t * 1024 + nn] = h;
          } else {
            ((u16*)C3)[(size_t)t * 1024 + nn] = h;
          }
        }
      } else {
        float bs = bias ? bias[n] : 0.f;
#pragma unroll
        for (int r = 0; r < 4; ++r) {
          int t = rb + r;
          float v = acc[i][j][r] + bs;
          ((float*)C)[(size_t)t * N + n] = v;
        }
      }
    }
  }
}

// ================= gemm128f8: MX-fp8, 32B-granule swizzle, BK=128 =================
// MODE 2: conv A-addressing (A = fp8 Qpad halo), epilogue gelu(silu(v+bias)) -> fp8 out.
// MODE 5: fused logits+softmax-partial: w = exp(acc*episcale); reads vals tile
//         (VREMAP: halo row remap), per-column block reduce -> PZp/PNp[m_tile][col].
template<int MODE, int VREMAP>
__global__ __launch_bounds__(256, 2)
void gemm128f8(const u8* __restrict__ A, const u8* __restrict__ B,
               void* __restrict__ C, const float* __restrict__ bias, float episcale,
               const u16* __restrict__ vals, float* __restrict__ PZp, float* __restrict__ PNp,
               int M, int N, int K, int lda /*bytes*/)
{
  __shared__ alignas(16) char smem[32768];
  char* sA = smem;
  char* sB = smem + 16384;

  int nwg = gridDim.x;
  int bx = blockIdx.x;
  if ((nwg & 7) == 0) bx = (bx & 7) * (nwg >> 3) + (bx >> 3);
  int GN = N >> 7;
  int bm = bx / GN, bn = bx - bm * GN;
  int m0 = bm << 7, n0 = bn << 7;

  int tid = threadIdx.x;
  int lane = tid & 63, wid = tid >> 6;
  int wm = wid >> 1, wn = wid & 1;

  f32x4 acc[4][4] = {};

  int strow = tid >> 3;            // 0..31
  int stcolb = (tid & 7) << 4;     // byte col 0..112 within 128B row
  int bofm = m0 >> 12;

  const int KT = K >> 7;           // BK = 128 (bytes == elements)
  for (int kt = 0; kt < KT; ++kt) {
    int k0 = kt << 7;
    const char* Ab;
    if (MODE == 2) {
      int tap = k0 >> 10;          // K = 3072 = 3 taps x 1024
      Ab = (const char*)A + (size_t)(m0 + 2 * bofm + tap) * lda + (k0 & 1023);
    } else {
      Ab = (const char*)A + (size_t)m0 * lda + k0;
    }
    const char* Bb = (const char*)B + (size_t)n0 * K + k0;
#pragma unroll
    for (int j = 0; j < 4; ++j) {
      int row = j * 32 + strow;
      int sw = (row & 3) << 5;     // XOR swizzle on 32B granules (involution)
      gload_lds16(Ab + (size_t)row * lda + (size_t)(stcolb ^ sw), sA + j * 4096 + wid * 1024);
      gload_lds16(Bb + (size_t)row * K + (size_t)(stcolb ^ sw), sB + j * 4096 + wid * 1024);
    }
    __syncthreads();
    {
      i32x8 av[4], bv[4];
      int cb = (lane >> 4) << 5;   // 32B K-chunk per lane group (one MX block)
#pragma unroll
      for (int i = 0; i < 4; ++i) {
        int r = (wm << 6) + (i << 4) + (lane & 15);
        const char* p = sA + r * 128 + (cb ^ ((r & 3) << 5));   // 32B contiguous, in order
        i32x4 lo = *(const i32x4*)p;
        i32x4 hi = *(const i32x4*)(p + 16);
        av[i] = i32x8{lo[0], lo[1], lo[2], lo[3], hi[0], hi[1], hi[2], hi[3]};
      }
#pragma unroll
      for (int j = 0; j < 4; ++j) {
        int r = (wn << 6) + (j << 4) + (lane & 15);
        const char* p = sB + r * 128 + (cb ^ ((r & 3) << 5));
        i32x4 lo = *(const i32x4*)p;
        i32x4 hi = *(const i32x4*)(p + 16);
        bv[j] = i32x8{lo[0], lo[1], lo[2], lo[3], hi[0], hi[1], hi[2], hi[3]};
      }
#pragma unroll
      for (int i = 0; i < 4; ++i)
#pragma unroll
        for (int j = 0; j < 4; ++j)
          acc[i][j] = mfma_mx(av[i], bv[j], acc[i][j]);
    }
    __syncthreads();
  }

  if (MODE == 2) {
#pragma unroll
    for (int i = 0; i < 4; ++i) {
      int rb = m0 + (wm << 6) + (i << 4) + ((lane >> 4) << 2);
#pragma unroll
      for (int j = 0; j < 4; ++j) {
        int n = n0 + (wn << 6) + (j << 4) + (lane & 15);
        float bs = bias ? bias[n] : 0.f;
#pragma unroll
        for (int r = 0; r < 4; ++r) {
          int t = rb + r;
          float v = acc[i][j][r] + bs;
          ((u8*)C)[(size_t)t * N + n] = f2fp8(geluf(siluf(v)));
        }
      }
    }
  } else {  // MODE 5: fused softmax partial (no max subtraction; logits are tiny)
    float zj[4] = {0.f, 0.f, 0.f, 0.f}, nj[4] = {0.f, 0.f, 0.f, 0.f};
#pragma unroll
    for (int i = 0; i < 4; ++i) {
      int rb = m0 + (wm << 6) + (i << 4) + ((lane >> 4) << 2);
#pragma unroll
      for (int j = 0; j < 4; ++j) {
        int n = n0 + (wn << 6) + (j << 4) + (lane & 15);
#pragma unroll
        for (int r = 0; r < 4; ++r) {
          int t = rb + r;
          float w = __expf(acc[i][j][r] * episcale);
          size_t vrow = VREMAP ? ((size_t)t + 2 * (t >> 12) + 1) : (size_t)t;
          float v = bf2f(vals[vrow * 1024 + n]);
          zj[j] += w;
          nj[j] += v * w;
        }
      }
    }
    __syncthreads();                 // LDS free after K-loop's trailing sync + this
    float2* arr = (float2*)smem;     // [128 cols][8 contributors]
    int g = (wm << 2) + (lane >> 4); // 0..7
#pragma unroll
    for (int j = 0; j < 4; ++j) {
      int cl = (wn << 6) + (j << 4) + (lane & 15);   // 0..127
      arr[cl * 8 + g] = make_float2(zj[j], nj[j]);
    }
    __syncthreads();
    if (tid < 128) {
      float Z = 0.f, Nn = 0.f;
#pragma unroll
      for (int g2 = 0; g2 < 8; ++g2) { float2 p = arr[tid * 8 + g2]; Z += p.x; Nn += p.y; }
      size_t o = (size_t)(m0 >> 7) * 1024 + n0 + tid;
      PZp[o] = Z;
      PNp[o] = Nn;
    }
  }
}

// ---------------- combine: summ = (sum PN / sum PZ) * (mul ? mul : 1) ----------------
__global__ void summ_combine(const float* __restrict__ pz, const float* __restrict__ pn,
                             const float* __restrict__ mul, float* __restrict__ summ)
{
  int idx = blockIdx.x * 256 + threadIdx.x;  // 0..4095 : b*1024+e
  int b = idx >> 10, e = idx & 1023;
  float Z = 0.f, Nn = 0.f;
  for (int bm = b * 32; bm < b * 32 + 32; ++bm) {
    Z += pz[(size_t)bm * 1024 + e];
    Nn += pn[(size_t)bm * 1024 + e];
  }
  float r = Nn / Z;
  summ[idx] = mul ? r * mul[idx] : r;
}

// ---------------- elementwise ----------------
// GP8 = fp8(gelu(O * s1[b,:]))
__global__ void pk(const u16* __restrict__ O, const float* __restrict__ s1,
                   u8* __restrict__ GP8)
{
  size_t idx = (size_t)blockIdx.x * 256 + threadIdx.x;
  size_t base = idx * 8;
  int t = (int)(base >> 10);
  int b = t >> 12;
  int e = (int)(base & 1023);
  const float* sp = s1 + b * 1024 + e;
  u16x8 ov = *(const u16x8*)(O + base);
  u8x8 gv;
#pragma unroll
  for (int j = 0; j < 8; ++j) {
    gv[j] = f2fp8(geluf(bf2f(ov[j]) * sp[j]));
  }
  *(u8x8*)(GP8 + base) = gv;
}

// L = silu(G) * summ2[b,:]
__global__ void lk(const u16* __restrict__ G, const float* __restrict__ s2,
                   u16* __restrict__ L)
{
  size_t idx = (size_t)blockIdx.x * 256 + threadIdx.x;
  size_t base = idx * 8;
  int t = (int)(base >> 10);
  int b = t >> 12;
  int e = (int)(base & 1023);
  const float* sp = s2 + b * 1024 + e;
  u16x8 gvv = *(const u16x8*)(G + base);
  u16x8 lv;
#pragma unroll
  for (int j = 0; j < 8; ++j) {
    lv[j] = f2bf(siluf(bf2f(gvv[j])) * sp[j]);
  }
  *(u16x8*)(L + base) = lv;
}

// ---------------- launch ----------------
extern "C" void kernel_launch(void* const* d_in, const int* in_sizes, int n_in,
                              void* d_out, int out_size, void* d_ws, size_t ws_size,
                              hipStream_t stream)
{
  const float* x     = (const float*)d_in[0];
  const float* Wq    = (const float*)d_in[1];
  const float* Wqb   = (const float*)d_in[2];
  const float* Wo    = (const float*)d_in[3];
  const float* Wob   = (const float*)d_in[4];
  const float* Wg    = (const float*)d_in[5];
  const float* Wgb   = (const float*)d_in[6];
  const float* wa    = (const float*)d_in[7];
  const float* wb    = (const float*)d_in[8];
  const float* Wout  = (const float*)d_in[9];
  const float* Woutb = (const float*)d_in[10];
  const float* convw = (const float*)d_in[11];
  const float* convb = (const float*)d_in[12];

  char* ws = (char*)d_ws;
  size_t off = 0;
  auto alloc = [&](size_t bytes) -> char* {
    char* p = ws + off;
    off += (bytes + 255) & ~(size_t)255;
    return p;
  };

  u16* QPAD  = (u16*)alloc((size_t)4 * SPAD * 1024 * 2);  // bf16 Q, halo layout
  u8*  QPAD8 = (u8*)alloc((size_t)4 * SPAD * 1024);       // fp8 Q, halo layout (conv A)
  u16* OB   = (u16*)alloc((size_t)NT * 1024 * 2);         // O -> later L
  u16* GB   = (u16*)alloc((size_t)NT * 1024 * 2);         // G
  u16* XB   = (u16*)alloc((size_t)NT * 1024 * 2);         // x bf16 -> GA8 -> GP8
  u16* WALL = (u16*)alloc((size_t)4 * 1024 * 1024 * 2);   // bf16 [Wq,Wo,Wg,Wout]
  u8*  WAB8 = (u8*)alloc((size_t)2 * 1024 * 1024);        // fp8 [wa, wb] (unscaled)
  u8*  WC8  = (u8*)alloc((size_t)1024 * 3072);            // fp8 conv weights
  float* PZb = (float*)alloc((size_t)128 * 1024 * 4);     // per-m-tile softmax partials
  float* PNb = (float*)alloc((size_t)128 * 1024 * 4);
  float* S1 = (float*)alloc((size_t)4096 * 4);
  float* S2 = (float*)alloc((size_t)4096 * 4);

  if (off > ws_size) return;

  u16* WQOG   = WALL;                                 // [Wq,Wo,Wg] contiguous
  u16* WOUTB_ = WALL + (size_t)3 * 1048576;
  u8*  WA8    = WAB8;
  u8*  WB8    = WAB8 + (size_t)1048576;

  u8* GA8 = (u8*)XB;   // conv output fp8 (x dead after QOG)
  u8* GP8 = (u8*)XB;   // pk output fp8 (GA8 dead after wa-logits)
  u16* LB = OB;        // L aliases O (O dead after wb pass)

  const float scale = 0.03125f;  // 1/sqrt(1024)

  // 1. converts
  cvtk<<<16384, 256, 0, stream>>>(x, XB, 4194304, 1.0f);
  cvt_misc<<<10272, 256, 0, stream>>>(Wq, Wo, Wg, Wout, wa, wb, convw,
                                      WALL, WAB8, WC8, QPAD);

  // 2. fused Q/O/G GEMM (bf16): Q -> QPAD bf16 halo; O; G
  gemm128<4><<<128 * 24, 256, 0, stream>>>(XB, WQOG, QPAD, Wqb, OB, GB, Wob, Wgb,
                                           NT, 3072, 1024, 1024);

  // 2b. Q bf16 halo -> fp8 halo (linear copy incl. zero halos)
  cvt_q8<<<8196, 256, 0, stream>>>(QPAD, QPAD8);

  // 3. conv as MX-fp8 GEMM (A = fp8 Qpad, K = 3072), epilogue gelu(silu(.)) -> GA8
  gemm128f8<2, 0><<<128 * 8, 256, 0, stream>>>(QPAD8, WC8, GA8, convb, 1.0f,
                                               nullptr, nullptr, nullptr,
                                               NT, 1024, 3072, 1024);

  // 4+5a. logits A + fused softmax partials (vals = QPAD bf16, halo remap)
  gemm128f8<5, 1><<<128 * 8, 256, 0, stream>>>(GA8, WA8, nullptr, nullptr, scale,
                                               QPAD, PZb, PNb,
                                               NT, 1024, 1024, 1024);
  summ_combine<<<16, 256, 0, stream>>>(PZb, PNb, nullptr, S1);

  // 6. GP8 = fp8(gelu(O * summ1))
  pk<<<8192, 256, 0, stream>>>(OB, S1, GP8);

  // 7+8a. logits B + fused softmax partials (vals = OB plain)
  gemm128f8<5, 0><<<128 * 8, 256, 0, stream>>>(GP8, WB8, nullptr, nullptr, scale,
                                               OB, PZb, PNb,
                                               NT, 1024, 1024, 1024);
  summ_combine<<<16, 256, 0, stream>>>(PZb, PNb, S1, S2);

  // 9. L = silu(G) * summ2
  lk<<<8192, 256, 0, stream>>>(GB, S2, LB);

  // 10. out = L @ Wout^T + b  (bf16 GEMM, f32 out)
  gemm128<3><<<128 * 8, 256, 0, stream>>>(LB, WOUTB_, d_out, Woutb, nullptr, nullptr,
                                          nullptr, nullptr, NT, 1024, 1024, 1024);
}